// Round 9
// baseline (1439.606 us; speedup 1.0000x reference)
//
#include <hip/hip_runtime.h>
#include <hip/hip_bf16.h>
#include <math.h>

// Problem constants
#define V_  32000
#define D_  512
#define NL_ 4
#define K_  32
#define B_  2
#define L_  1024
#define FF_ 2048
#define MR_ (B_ * L_)   // 2048 total rows

typedef __bf16 bf16_t;
typedef __bf16 bf16x8 __attribute__((ext_vector_type(8)));
typedef float  f32x4  __attribute__((ext_vector_type(4)));

#define FLAG_TANH   1
#define FLAG_GELU   2
#define FLAG_INV    8
#define FLAG_CAUSAL 16
#define FLAG_TRI    64   // triangular score GEMM: skip bx>by blocks, zero n>m
#define FLAG_HALFK  128  // split-K: this dispatch covers Kd/2 (z selects chunk)
#define FLAG_VSPLIT 256  // fused t1|v: n<D -> tanh -> Cf; n>=D -> vT_bf via Cb

// async 16B global->LDS (wave-uniform LDS base + lane*16)
#define GLDS(gsrc, ldst) \
  __builtin_amdgcn_global_load_lds( \
      (const __attribute__((address_space(1))) unsigned int*)(const void*)(gsrc), \
      (__attribute__((address_space(3))) unsigned int*)(void*)(ldst), 16, 0, 0)

// ---------------------------------------------------------------------------
// Embedding gather
// ---------------------------------------------------------------------------
__global__ void gather_kernel(const int* __restrict__ tokens,
                              const float* __restrict__ embed,
                              float* __restrict__ h) {
    int row = blockIdx.x;
    int t = tokens[row];
    const float4* src = (const float4*)(embed + (size_t)t * D_);
    float4* dst = (float4*)(h + (size_t)row * D_);
    dst[threadIdx.x] = src[threadIdx.x];
}

// ---------------------------------------------------------------------------
// fp32 -> bf16 bulk convert (row-major, no transpose). count % 2048 == 0.
// ---------------------------------------------------------------------------
__global__ __launch_bounds__(256) void cvt_kernel(const float* __restrict__ in,
                                                  bf16_t* __restrict__ out) {
    size_t i = ((size_t)blockIdx.x * 256 + threadIdx.x) * 8;
    float4 f0 = ((const float4*)(in + i))[0];
    float4 f1 = ((const float4*)(in + i))[1];
    bf16x8 ov;
    ov[0] = (bf16_t)f0.x; ov[1] = (bf16_t)f0.y;
    ov[2] = (bf16_t)f0.z; ov[3] = (bf16_t)f0.w;
    ov[4] = (bf16_t)f1.x; ov[5] = (bf16_t)f1.y;
    ov[6] = (bf16_t)f1.z; ov[7] = (bf16_t)f1.w;
    *(bf16x8*)(out + i) = ov;
}

// ---------------------------------------------------------------------------
// Bias concat: o[i][0:D) = a[i], o[i][D:2D) = b[i]
// ---------------------------------------------------------------------------
__global__ void bconcat_kernel(const float* __restrict__ a,
                               const float* __restrict__ b,
                               float* __restrict__ o) {
    int i = blockIdx.x, t = threadIdx.x;   // block 512
    o[(size_t)i * 2 * D_ + t]       = a[(size_t)i * D_ + t];
    o[(size_t)i * 2 * D_ + D_ + t]  = b[(size_t)i * D_ + t];
}

// ---------------------------------------------------------------------------
// LayerNorm over D=512; optional fp32 and bf16 outputs.
// ---------------------------------------------------------------------------
__global__ __launch_bounds__(256) void ln_kernel(const float* __restrict__ in,
                                                 const float* __restrict__ g,
                                                 const float* __restrict__ b,
                                                 float* __restrict__ outf,
                                                 bf16_t* __restrict__ outb) {
    int row = blockIdx.x, tid = threadIdx.x;
    const float* rp = in + (size_t)row * D_;
    float v0 = rp[tid], v1 = rp[tid + 256];
    float s = v0 + v1, q = v0 * v0 + v1 * v1;
#pragma unroll
    for (int o = 32; o > 0; o >>= 1) {
        s += __shfl_down(s, o, 64);
        q += __shfl_down(q, o, 64);
    }
    __shared__ float ss[4], sq[4];
    if ((tid & 63) == 0) { ss[tid >> 6] = s; sq[tid >> 6] = q; }
    __syncthreads();
    float ts = ss[0] + ss[1] + ss[2] + ss[3];
    float tq = sq[0] + sq[1] + sq[2] + sq[3];
    float mean = ts * (1.0f / D_);
    float var = tq * (1.0f / D_) - mean * mean;
    float rstd = rsqrtf(var + 1e-5f);
    float o0 = (v0 - mean) * rstd * g[tid] + b[tid];
    float o1 = (v1 - mean) * rstd * g[tid + 256] + b[tid + 256];
    if (outf) {
        outf[(size_t)row * D_ + tid]       = o0;
        outf[(size_t)row * D_ + tid + 256] = o1;
    }
    if (outb) {
        outb[(size_t)row * D_ + tid]       = (bf16_t)o0;
        outb[(size_t)row * D_ + tid + 256] = (bf16_t)o1;
    }
}

// ---------------------------------------------------------------------------
// Fused split-K sum + LayerNorm:
//   hnew = h + p0 + p1 + bias;  h = hnew (if hout)
//   LN(hnew, g, b) -> outf (fp32, nullable), outb (bf16)
// One row per block, 256 threads (2 elems/thread). Same reduction as ln_kernel
// -> numerics identical to sumk followed by ln.
// ---------------------------------------------------------------------------
__global__ __launch_bounds__(256) void sumk_ln_kernel(
    const float* __restrict__ p0, const float* __restrict__ p1,
    const float* __restrict__ bias, float* __restrict__ h,
    const float* __restrict__ g, const float* __restrict__ b,
    float* __restrict__ outf, bf16_t* __restrict__ outb) {
    int row = blockIdx.x, tid = threadIdx.x;
    size_t o = (size_t)row * D_;
    float v0 = h[o + tid]       + p0[o + tid]       + p1[o + tid]       + bias[tid];
    float v1 = h[o + tid + 256] + p0[o + tid + 256] + p1[o + tid + 256] + bias[tid + 256];
    h[o + tid]       = v0;
    h[o + tid + 256] = v1;
    float s = v0 + v1, q = v0 * v0 + v1 * v1;
#pragma unroll
    for (int of = 32; of > 0; of >>= 1) {
        s += __shfl_down(s, of, 64);
        q += __shfl_down(q, of, 64);
    }
    __shared__ float ss[4], sq[4];
    if ((tid & 63) == 0) { ss[tid >> 6] = s; sq[tid >> 6] = q; }
    __syncthreads();
    float ts = ss[0] + ss[1] + ss[2] + ss[3];
    float tq = sq[0] + sq[1] + sq[2] + sq[3];
    float mean = ts * (1.0f / D_);
    float var = tq * (1.0f / D_) - mean * mean;
    float rstd = rsqrtf(var + 1e-5f);
    float o0 = (v0 - mean) * rstd * g[tid] + b[tid];
    float o1 = (v1 - mean) * rstd * g[tid + 256] + b[tid + 256];
    if (outf) {
        outf[o + tid]       = o0;
        outf[o + tid + 256] = o1;
    }
    outb[o + tid]       = (bf16_t)o0;
    outb[o + tid + 256] = (bf16_t)o1;
}

// ---------------------------------------------------------------------------
// Transpose + fp32->bf16 convert: in fp32 [R][C-strided] -> out bf16 [.][R]
// grid (cols/32, R/32, Z), block 256
// ---------------------------------------------------------------------------
__global__ __launch_bounds__(256) void tconv_kernel(const float* __restrict__ in,
                                                    bf16_t* __restrict__ out,
                                                    int R, int C,
                                                    size_t inz, size_t outz) {
    __shared__ float t[32][33];
    const float* ip = in + (size_t)blockIdx.z * inz;
    bf16_t* op = out + (size_t)blockIdx.z * outz;
    int r0 = blockIdx.y * 32, c0 = blockIdx.x * 32;
    int tx = threadIdx.x & 31, ty = threadIdx.x >> 5;  // ty in [0,8)
#pragma unroll
    for (int rr = 0; rr < 4; ++rr)
        t[ty + rr * 8][tx] = ip[(size_t)(r0 + ty + rr * 8) * C + c0 + tx];
    __syncthreads();
#pragma unroll
    for (int rr = 0; rr < 4; ++rr)
        op[(size_t)(c0 + ty + rr * 8) * R + r0 + tx] = (bf16_t)t[tx][ty + rr * 8];
}

// ---------------------------------------------------------------------------
// MFMA bf16 GEMM: C[M,N] = epilogue(A[M,K] @ B^T[N,K])
//   BK=32 path: head (NBUF=3 measured 216 us — structural ceiling).
//   BK=64 path: layer GEMMs (r8 measured best; XOR-swizzled LDS, see r8 notes)
// flags: 1 tanh, 2 gelu, 8 inv, 16 causal, 64 tri, 128 half-K,
//        256 vsplit (t1 half -> tanh -> Cf; v half -> transposed bf16 via Cb).
// swz: bijective XCD-chunked block remap, m-fast within each n-panel chunk.
// ---------------------------------------------------------------------------
template<int BM, int BN, int NBUF, int BK, bool BF32>
__global__ __launch_bounds__(256) void mgemm(
    const bf16_t* __restrict__ A, const void* __restrict__ Bp,
    const float* __restrict__ bias, const float* __restrict__ res1,
    const float* __restrict__ res2, float* __restrict__ Cf,
    bf16_t* __restrict__ Cb, int M, int N, int Kd, int flags,
    long long strA, long long strB, long long strC, int swz) {
    __shared__ bf16_t sA[NBUF][BM * BK];
    __shared__ bf16_t sB[NBUF][BN * BK];
    const int tid = threadIdx.x;
    const int wave = tid >> 6, lane = tid & 63;
    const int lrow = lane & 15, quad = lane >> 4;
    int bx = blockIdx.x, by = blockIdx.y;
    if (swz) {
        int gx = gridDim.x, gy = gridDim.y;
        int nwg = gx * gy;
        int lid = by * gx + bx;
        int q = nwg >> 3, r = nwg & 7;
        int xcd = lid & 7, slot = lid >> 3;
        int base = (xcd < r) ? xcd * (q + 1) : r * (q + 1) + (xcd - r) * q;
        int nid = base + slot;       // contiguous chunk per XCD
        bx = nid / gy;               // n varies slowly
        by = nid - bx * gy;          // m fast within an n-panel
    }
    if ((flags & FLAG_TRI) && bx > by) return;   // strictly-upper: never read
    const int m0 = by * BM, n0 = bx * BN;
    const int z = blockIdx.z;
    A += (size_t)z * strA;
    const bf16_t* Bb = (const bf16_t*)Bp + (BF32 ? 0 : (size_t)z * strB);
    const float*  Bf = (const float*)Bp  + (BF32 ? (size_t)z * strB : 0);
    constexpr int TM = BM / 32, TN = BN / 32;  // 16x16 tiles per wave dim
    const int wm = (wave >> 1) * (BM / 2), wn = (wave & 1) * (BN / 2);
    f32x4 acc[TM][TN] = {};

    if constexpr (BF32) {
        // -------- fallback: single-buffered, fp32 B convert-staging --------
        for (int k0 = 0; k0 < Kd; k0 += 32) {
#pragma unroll
            for (int rb = 0; rb < BM / 64; ++rb) {
                int rowblk = wave * (BM / 64) + rb;
                int ml = rowblk * 16 + (lane >> 2);
                int qs = (lane & 3) ^ ((ml >> 1) & 3);
                GLDS(A + (size_t)(m0 + ml) * Kd + k0 + qs * 8, &sA[0][rowblk * 512]);
            }
#pragma unroll
            for (int rb = 0; rb < (BN * 4) / 256; ++rb) {
                int s = rb * 256 + tid;
                int nl = s >> 2, ql = s & 3;
                int qs = ql ^ ((nl >> 1) & 3);
                const float* src = Bf + (size_t)(n0 + nl) * Kd + k0 + qs * 8;
                float4 f0 = ((const float4*)src)[0];
                float4 f1 = ((const float4*)src)[1];
                bf16x8 ov;
                ov[0] = (bf16_t)f0.x; ov[1] = (bf16_t)f0.y;
                ov[2] = (bf16_t)f0.z; ov[3] = (bf16_t)f0.w;
                ov[4] = (bf16_t)f1.x; ov[5] = (bf16_t)f1.y;
                ov[6] = (bf16_t)f1.z; ov[7] = (bf16_t)f1.w;
                *(bf16x8*)(&sB[0][s * 8]) = ov;
            }
            __syncthreads();
            bf16x8 af[TM], bv[TN];
#pragma unroll
            for (int i = 0; i < TM; ++i) {
                int row = wm + i * 16 + lrow;
                af[i] = *(const bf16x8*)(&sA[0][(row * 4 + (quad ^ ((row >> 1) & 3))) * 8]);
            }
#pragma unroll
            for (int j = 0; j < TN; ++j) {
                int rown = wn + j * 16 + lrow;
                bv[j] = *(const bf16x8*)(&sB[0][(rown * 4 + (quad ^ ((rown >> 1) & 3))) * 8]);
            }
#pragma unroll
            for (int i = 0; i < TM; ++i)
#pragma unroll
                for (int j = 0; j < TN; ++j)
                    acc[i][j] = __builtin_amdgcn_mfma_f32_16x16x32_bf16(af[i], bv[j], acc[i][j], 0, 0, 0);
            __syncthreads();
        }
    } else if constexpr (BK == 64) {
        // -------- BK=64: 8-row GLDS groups, XOR-swizzled chunks --------
        int kend = Kd;
        if (flags & FLAG_CAUSAL) { int ke = m0 + BM; kend = ke < Kd ? ke : Kd; }
        if (flags & FLAG_HALFK) kend = Kd >> 1;
        const int nk = kend >> 6;
        constexpr int NLD = BM / 32 + BN / 32;   // GLDS per wave per stage
        auto stage = [&](int t, int buf) {
            const int k0 = t << 6;
#pragma unroll
            for (int rb = 0; rb < BM / 32; ++rb) {
                int r0 = (wave * (BM / 32) + rb) * 8;
                int row = r0 + (lane >> 3);
                int cs_ = (lane & 7) ^ (row & 7);
                GLDS(A + (size_t)(m0 + row) * Kd + k0 + cs_ * 8, &sA[buf][r0 * 64]);
            }
#pragma unroll
            for (int rb = 0; rb < BN / 32; ++rb) {
                int r0 = (wave * (BN / 32) + rb) * 8;
                int row = r0 + (lane >> 3);
                int cs_ = (lane & 7) ^ (row & 7);
                GLDS(Bb + (size_t)(n0 + row) * Kd + k0 + cs_ * 8, &sB[buf][r0 * 64]);
            }
        };
        auto compute = [&](int buf) {
            const bf16_t* sAc = sA[buf];
            const bf16_t* sBc = sB[buf];
            bf16x8 a0[TM], a1[TM], b0[TN], b1[TN];
#pragma unroll
            for (int i = 0; i < TM; ++i) {
                int row = wm + i * 16 + lrow;
                a0[i] = *(const bf16x8*)(sAc + row * 64 + ((quad       ^ (row & 7)) * 8));
                a1[i] = *(const bf16x8*)(sAc + row * 64 + (((4 | quad) ^ (row & 7)) * 8));
            }
#pragma unroll
            for (int j = 0; j < TN; ++j) {
                int rown = wn + j * 16 + lrow;
                b0[j] = *(const bf16x8*)(sBc + rown * 64 + ((quad       ^ (rown & 7)) * 8));
                b1[j] = *(const bf16x8*)(sBc + rown * 64 + (((4 | quad) ^ (rown & 7)) * 8));
            }
#pragma unroll
            for (int i = 0; i < TM; ++i)
#pragma unroll
                for (int j = 0; j < TN; ++j)
                    acc[i][j] = __builtin_amdgcn_mfma_f32_16x16x32_bf16(a0[i], b0[j], acc[i][j], 0, 0, 0);
#pragma unroll
            for (int i = 0; i < TM; ++i)
#pragma unroll
                for (int j = 0; j < TN; ++j)
                    acc[i][j] = __builtin_amdgcn_mfma_f32_16x16x32_bf16(a1[i], b1[j], acc[i][j], 0, 0, 0);
        };
        for (int t = 0; t < NBUF - 1 && t < nk; ++t) stage(t, t);
        int bcur = 0;
        for (int t = 0; t < nk; ++t) {
            const int nxt = t + NBUF - 1;
            if (nxt < nk) {
                int bn = bcur + NBUF - 1; if (bn >= NBUF) bn -= NBUF;
                stage(nxt, bn);
            }
            const int last = (nxt < nk) ? nxt : nk - 1;
            const int ahead = last - t;
            if (ahead >= 2)      asm volatile("s_waitcnt vmcnt(%0)" :: "n"(2 * NLD) : "memory");
            else if (ahead == 1) asm volatile("s_waitcnt vmcnt(%0)" :: "n"(1 * NLD) : "memory");
            else                 asm volatile("s_waitcnt vmcnt(0)" ::: "memory");
            __builtin_amdgcn_s_barrier();
            compute(bcur);
            asm volatile("s_waitcnt lgkmcnt(0)" ::: "memory");
            __builtin_amdgcn_s_barrier();
            bcur = (bcur + 1 == NBUF) ? 0 : bcur + 1;
        }
    } else {
        // -------- BK=32 (head) --------
        int kend = Kd;
        if (flags & FLAG_CAUSAL) { int ke = m0 + BM; kend = ke < Kd ? ke : Kd; }
        if (flags & FLAG_HALFK) kend = Kd >> 1;
        const int nk = kend >> 5;
        constexpr int NLD = BM / 64 + BN / 64;   // GLDS ops per wave per stage
        auto stage = [&](int t, int buf) {
            const int k0 = t << 5;
#pragma unroll
            for (int rb = 0; rb < BM / 64; ++rb) {
                int rowblk = wave * (BM / 64) + rb;
                int ml = rowblk * 16 + (lane >> 2);
                int qs = (lane & 3) ^ ((ml >> 1) & 3);
                GLDS(A + (size_t)(m0 + ml) * Kd + k0 + qs * 8, &sA[buf][rowblk * 512]);
            }
#pragma unroll
            for (int rb = 0; rb < BN / 64; ++rb) {
                int rowblk = wave * (BN / 64) + rb;
                int nl = rowblk * 16 + (lane >> 2);
                int qs = (lane & 3) ^ ((nl >> 1) & 3);
                GLDS(Bb + (size_t)(n0 + nl) * Kd + k0 + qs * 8, &sB[buf][rowblk * 512]);
            }
        };
        auto compute = [&](int buf) {
            const bf16_t* sAc = sA[buf];
            const bf16_t* sBc = sB[buf];
            bf16x8 af[TM], bv[TN];
#pragma unroll
            for (int i = 0; i < TM; ++i) {
                int row = wm + i * 16 + lrow;
                af[i] = *(const bf16x8*)(sAc + (row * 4 + (quad ^ ((row >> 1) & 3))) * 8);
            }
#pragma unroll
            for (int j = 0; j < TN; ++j) {
                int rown = wn + j * 16 + lrow;
                bv[j] = *(const bf16x8*)(sBc + (rown * 4 + (quad ^ ((rown >> 1) & 3))) * 8);
            }
#pragma unroll
            for (int i = 0; i < TM; ++i)
#pragma unroll
                for (int j = 0; j < TN; ++j)
                    acc[i][j] = __builtin_amdgcn_mfma_f32_16x16x32_bf16(af[i], bv[j], acc[i][j], 0, 0, 0);
        };
        if constexpr (NBUF == 2) {
            stage(0, 0);
            int cur = 0;
            for (int t = 0; t < nk; ++t) {
                if (t + 1 < nk) {
                    stage(t + 1, cur ^ 1);
                    asm volatile("s_waitcnt vmcnt(%0)" :: "n"(NLD) : "memory");
                } else {
                    asm volatile("s_waitcnt vmcnt(0)" ::: "memory");
                }
                __builtin_amdgcn_s_barrier();
                compute(cur);
                asm volatile("s_waitcnt lgkmcnt(0)" ::: "memory");
                __builtin_amdgcn_s_barrier();
                cur ^= 1;
            }
        } else {
            // NBUF=3: triple buffer (explicit rotation), 2 stages in flight
            stage(0, 0);
            if (nk > 1) stage(1, 1);
            int b0 = 0;
            for (int t = 0; t < nk; ++t) {
                const int nxt = t + 2;
                if (nxt < nk) {
                    int bn = b0 + 2; if (bn >= 3) bn -= 3;
                    stage(nxt, bn);
                }
                const int last = (nxt < nk) ? nxt : nk - 1;
                const int ahead = last - t;
                if (ahead >= 2)      asm volatile("s_waitcnt vmcnt(%0)" :: "n"(2 * NLD) : "memory");
                else if (ahead == 1) asm volatile("s_waitcnt vmcnt(%0)" :: "n"(1 * NLD) : "memory");
                else                 asm volatile("s_waitcnt vmcnt(0)" ::: "memory");
                __builtin_amdgcn_s_barrier();
                compute(b0);
                asm volatile("s_waitcnt lgkmcnt(0)" ::: "memory");
                __builtin_amdgcn_s_barrier();
                b0 = (b0 == 2) ? 0 : b0 + 1;
            }
        }
    }

    // --- epilogue: C/D layout col=lane&15, row=quad*4+reg ---
    const size_t zo = (size_t)z * strC;
#pragma unroll
    for (int i = 0; i < TM; ++i) {
#pragma unroll
        for (int reg = 0; reg < 4; ++reg) {
            int m = m0 + wm + i * 16 + quad * 4 + reg;
            float rs = (flags & FLAG_INV) ? rsqrtf((float)(m + 1) * (float)K_) : 1.0f;
#pragma unroll
            for (int j = 0; j < TN; ++j) {
                int n = n0 + wn + j * 16 + lrow;
                float vv = acc[i][j][reg];
                if (bias) vv += bias[n];
                vv *= rs;
                if (flags & FLAG_VSPLIT) {
                    if (n < D_) {
                        Cf[zo + (size_t)m * N + n] = tanhf(vv);
                    } else {
                        int bb = m >> 10, l = m & (L_ - 1);   // L_ = 1024
                        Cb[((size_t)bb * D_ + (n - D_)) * L_ + l] = (bf16_t)vv;
                    }
                    continue;
                }
                if (flags & FLAG_TANH) vv = tanhf(vv);
                else if (flags & FLAG_GELU) vv = 0.5f * vv * (1.0f + erff(vv * 0.7071067811865476f));
                if ((flags & FLAG_TRI) && n > m) vv = 0.f;
                size_t idx = zo + (size_t)m * N + n;
                if (res1) vv += res1[idx];
                if (res2) vv += res2[idx];
                if (Cf) Cf[idx] = vv;
                if (Cb) Cb[idx] = (bf16_t)vv;
            }
        }
    }
}

// ---------------------------------------------------------------------------
// Phase kernel: 4 rows per block (256 threads). Writes bf16 [cos|sin] into
// csb [row][64]. t1 rows strided 2*D (fused t1|v buffer).
// ---------------------------------------------------------------------------
__global__ __launch_bounds__(256) void phase_kernel(const float* __restrict__ t1,
                             const float* __restrict__ w2,
                             const float* __restrict__ b2,
                             const float* __restrict__ ps,
                             const float* __restrict__ cs,
                             int layer,
                             bf16_t* __restrict__ csb) {
    int tid = threadIdx.x;
    int rl = tid >> 6;                   // 0..3: row within block
    int k = tid & 31, hh = (tid >> 5) & 1;
    int row = blockIdx.x * 4 + rl;
    int l = row & (L_ - 1);
    const float* tr = t1 + (size_t)row * (2 * D_);
    float acc = 0.f;
    for (int d = hh * 256; d < hh * 256 + 256; ++d)
        acc = fmaf(tr[d], w2[d * K_ + k], acc);
    __shared__ float red[256];
    red[tid] = acc;
    __syncthreads();
    if (hh == 0) {
        float zz = red[rl * 64 + k] + red[rl * 64 + 32 + k] + b2[k];
        float cp = tanhf(zz) * 3.14159265358979323846f;
        float freq = expf(-(float)k * (9.210340371976184f / (float)K_));
        float tp = ps[layer] * (float)l * freq + cs[layer] * cp;
        csb[(size_t)row * 64 + k]      = (bf16_t)cosf(tp);
        csb[(size_t)row * 64 + 32 + k] = (bf16_t)sinf(tp);
    }
}

// ---------------------------------------------------------------------------
extern "C" void kernel_launch(void* const* d_in, const int* in_sizes, int n_in,
                              void* d_out, int out_size, void* d_ws, size_t ws_size,
                              hipStream_t stream) {
    const int*   tokens        = (const int*)d_in[0];
    const float* embed         = (const float*)d_in[1];
    const float* ln1_g         = (const float*)d_in[2];
    const float* ln1_b         = (const float*)d_in[3];
    const float* cp_w1         = (const float*)d_in[4];
    const float* cp_b1         = (const float*)d_in[5];
    const float* cp_w2         = (const float*)d_in[6];
    const float* cp_b2         = (const float*)d_in[7];
    const float* pos_scale     = (const float*)d_in[8];
    const float* content_scale = (const float*)d_in[9];
    const float* val_w         = (const float*)d_in[10];
    const float* val_b         = (const float*)d_in[11];
    const float* oln_g         = (const float*)d_in[12];
    const float* oln_b         = (const float*)d_in[13];
    const float* out_w         = (const float*)d_in[14];
    const float* out_b         = (const float*)d_in[15];
    const float* ln2_g         = (const float*)d_in[16];
    const float* ln2_b         = (const float*)d_in[17];
    const float* ffn_w1        = (const float*)d_in[18];
    const float* ffn_b1        = (const float*)d_in[19];
    const float* ffn_w2        = (const float*)d_in[20];
    const float* ffn_b2        = (const float*)d_in[21];
    const float* no_g          = (const float*)d_in[22];
    const float* no_b          = (const float*)d_in[23];
    const float* head_b        = (const float*)d_in[24];
    float* out = (float*)d_out;

    // Scratch in d_out (dead before head GEMM writes). hn_bf + emb_bf in d_ws.
    float* h   = out;                        // MR*D fp32
    float* x   = h  + (size_t)MR_ * D_;      // MR*D fp32
    float* t1v = x  + (size_t)MR_ * D_;      // MR*2D fp32 (t1 | v-slot unused)
    float* r   = t1v + (size_t)MR_ * 2 * D_; // MR*D fp32
    bf16_t* x_bf  = (bf16_t*)(r + (size_t)MR_ * D_);
    bf16_t* r_bf  = x_bf  + (size_t)MR_ * D_;
    bf16_t* y_bf  = r_bf  + (size_t)MR_ * D_;
    bf16_t* ff_bf = y_bf  + (size_t)MR_ * D_;          // MR*FF
    bf16_t* sc_bf = ff_bf + (size_t)MR_ * FF_;         // B*L*L
    bf16_t* vT_bf = sc_bf + (size_t)B_ * L_ * L_;      // B*D*L
    bf16_t* csb   = vT_bf + (size_t)B_ * D_ * L_;      // MR*64 (cos|sin bf16)
    bf16_t* wvT   = csb   + (size_t)MR_ * 64;          // NL*2*D*D (w1T|vwT per layer)
    bf16_t* owT   = wvT   + (size_t)NL_ * 2 * D_ * D_;
    bf16_t* f1T   = owT   + (size_t)NL_ * D_ * D_;     // NL*FF*D
    bf16_t* f2T   = f1T   + (size_t)NL_ * FF_ * D_;    // NL*D*FF
    float*  b1v   = (float*)(f2T + (size_t)NL_ * D_ * FF_); // NL*2D fp32
    float*  pK    = b1v + (size_t)NL_ * 2 * D_;        // 2*MR*D fp32 split-K partials
    bf16_t* hn_bf = (bf16_t*)d_ws;                     // MR*D (2 MB)
    bf16_t* emb_bf = hn_bf + (size_t)MR_ * D_;         // V*D bf16 (32.8 MB)
    const bool big_ws =
        ws_size >= ((size_t)MR_ * D_ + (size_t)V_ * D_) * sizeof(bf16_t);

    gather_kernel<<<MR_, 128, 0, stream>>>(tokens, embed, h);

    // Pre-transpose + convert all weights to bf16 [N][K]
    // Fused t1|v weight: layer i rows [0,D) = cp_w1^T, rows [D,2D) = val_w^T
    tconv_kernel<<<dim3(16, 16, NL_), 256, 0, stream>>>(cp_w1, wvT, D_, D_, (size_t)D_ * D_, (size_t)2 * D_ * D_);
    tconv_kernel<<<dim3(16, 16, NL_), 256, 0, stream>>>(val_w, wvT + (size_t)D_ * D_, D_, D_, (size_t)D_ * D_, (size_t)2 * D_ * D_);
    bconcat_kernel<<<NL_, 512, 0, stream>>>(cp_b1, val_b, b1v);
    tconv_kernel<<<dim3(16, 16, NL_), 256, 0, stream>>>(out_w, owT, D_, D_, (size_t)D_ * D_, (size_t)D_ * D_);
    tconv_kernel<<<dim3(64, 16, NL_), 256, 0, stream>>>(ffn_w1, f1T, D_, FF_, (size_t)D_ * FF_, (size_t)D_ * FF_);
    tconv_kernel<<<dim3(16, 64, NL_), 256, 0, stream>>>(ffn_w2, f2T, FF_, D_, (size_t)FF_ * D_, (size_t)FF_ * D_);
    // embed is already [N=V][K=D]: straight convert to bf16 for the head GEMM
    if (big_ws)
        cvt_kernel<<<(V_ * D_) / 2048, 256, 0, stream>>>(embed, emb_bf);

    for (int i = 0; i < NL_; ++i) {
        // x = LN(h): explicit only for layer 0 (fused into prev sumk_ln after)
        if (i == 0)
            ln_kernel<<<MR_, 256, 0, stream>>>(h, ln1_g, ln1_b, x, x_bf);
        // t1v = [tanh(x @ cp_w1 + cp_b1) | -] ; v-half written transposed
        // straight into vT_bf (FLAG_VSPLIT; vT passed via Cb)
        mgemm<64, 64, 3, 64, false><<<dim3(16, 32, 1), 256, 0, stream>>>(
            x_bf, wvT + (size_t)i * 2 * D_ * D_, b1v + (size_t)i * 2 * D_,
            nullptr, nullptr, t1v, vT_bf, MR_, 2 * D_, D_, FLAG_VSPLIT, 0, 0, 0, 1);
        // csb = bf16 [cos|sin] phases (reads t1 = cols [0,D) of t1v)
        phase_kernel<<<MR_ / 4, 256, 0, stream>>>(
            t1v, cp_w2 + (size_t)i * D_ * K_, cp_b2 + i * K_,
            pos_scale, content_scale, i, csb);
        // scores = tri(CS @ CS^T)  (K=64 GEMM; lower-triangle blocks only)
        mgemm<64, 64, 3, 64, false><<<dim3(L_ / 64, L_ / 64, B_), 256, 0, stream>>>(
            csb, csb, nullptr, nullptr, nullptr, nullptr, sc_bf,
            L_, L_, 64, FLAG_TRI,
            (long long)L_ * 64, (long long)L_ * 64, (long long)L_ * L_, 0);
        // r = (A @ v) * inv_norm  (batched over z; causal K-loop)
        mgemm<64, 64, 3, 64, false><<<dim3(8, 16, B_), 256, 0, stream>>>(
            sc_bf, vT_bf, nullptr, nullptr, nullptr, r, nullptr,
            L_, D_, L_, FLAG_INV | FLAG_CAUSAL,
            (long long)L_ * L_, (long long)D_ * L_, (long long)L_ * D_, 1);
        // r_bf = LN(r)
        ln_kernel<<<MR_, 256, 0, stream>>>(r, oln_g + i * D_, oln_b + i * D_, nullptr, r_bf);
        // h = h + x + (r_bf @ out_w + out_b)
        mgemm<64, 64, 3, 64, false><<<dim3(8, 32, 1), 256, 0, stream>>>(
            r_bf, owT + (size_t)i * D_ * D_, out_b + i * D_,
            h, x, h, nullptr, MR_, D_, D_, 0, 0, 0, 0, 1);
        // y_bf = LN(h)
        ln_kernel<<<MR_, 256, 0, stream>>>(h, ln2_g + i * D_, ln2_b + i * D_, nullptr, y_bf);
        // ff_bf = gelu(y @ ffn_w1 + b1)  (bf16 only)
        mgemm<128, 128, 3, 64, false><<<dim3(16, 16, 1), 256, 0, stream>>>(
            y_bf, f1T + (size_t)i * FF_ * D_, ffn_b1 + i * FF_,
            nullptr, nullptr, nullptr, ff_bf, MR_, FF_, D_, FLAG_GELU, 0, 0, 0, 1);
        // ffn2 split-K=2: pK[z] = ff[:, z*FF/2:(z+1)*FF/2] @ f2T[z-chunk]
        mgemm<64, 64, 3, 64, false><<<dim3(8, 32, 2), 256, 0, stream>>>(
            ff_bf, f2T + (size_t)i * D_ * FF_, nullptr,
            nullptr, nullptr, pK, nullptr, MR_, D_, FF_, FLAG_HALFK,
            (long long)(FF_ / 2), (long long)(FF_ / 2), (long long)MR_ * D_, 1);
        // h += pK0 + pK1 + ffn_b2, fused with next LN:
        //   layers 0..NL-2 -> next layer's ln1 (x, x_bf); last -> final LN (hn_bf)
        if (i < NL_ - 1) {
            sumk_ln_kernel<<<MR_, 256, 0, stream>>>(
                pK, pK + (size_t)MR_ * D_, ffn_b2 + i * D_, h,
                ln1_g + (i + 1) * D_, ln1_b + (i + 1) * D_, x, x_bf);
        } else {
            sumk_ln_kernel<<<MR_, 256, 0, stream>>>(
                pK, pK + (size_t)MR_ * D_, ffn_b2 + i * D_, h,
                no_g, no_b, nullptr, hn_bf);
        }
    }

    // out = hn @ embed^T + head_b
    if (big_ws) {
        mgemm<128, 128, 3, 32, false><<<dim3(V_ / 128, MR_ / 128, 1), 256, 0, stream>>>(
            hn_bf, emb_bf, head_b, nullptr, nullptr, out, nullptr,
            MR_, V_, D_, 0, 0, 0, 0, 1);
    } else {
        mgemm<128, 128, 1, 32, true><<<dim3(V_ / 128, MR_ / 128, 1), 256, 0, stream>>>(
            hn_bf, embed, head_b, nullptr, nullptr, out, nullptr,
            MR_, V_, D_, 0, 0, 0, 0, 1);
    }
}

// Round 10
// 1384.640 us; speedup vs baseline: 1.0397x; 1.0397x over previous
//
#include <hip/hip_runtime.h>
#include <hip/hip_bf16.h>
#include <math.h>

// Problem constants
#define V_  32000
#define D_  512
#define NL_ 4
#define K_  32
#define B_  2
#define L_  1024
#define FF_ 2048
#define MR_ (B_ * L_)   // 2048 total rows

typedef __bf16 bf16_t;
typedef __bf16 bf16x8 __attribute__((ext_vector_type(8)));
typedef float  f32x4  __attribute__((ext_vector_type(4)));

#define FLAG_TANH   1
#define FLAG_GELU   2
#define FLAG_INV    8
#define FLAG_CAUSAL 16
#define FLAG_TANHLO 32   // tanh applied only to columns n < D_ (fused t1|v GEMM)
#define FLAG_TRI    64   // triangular score GEMM: skip bx>by blocks, zero n>m
#define FLAG_HALFK  128  // split-K: this dispatch covers Kd/2 (z selects chunk)

// async 16B global->LDS (wave-uniform LDS base + lane*16)
#define GLDS(gsrc, ldst) \
  __builtin_amdgcn_global_load_lds( \
      (const __attribute__((address_space(1))) unsigned int*)(const void*)(gsrc), \
      (__attribute__((address_space(3))) unsigned int*)(void*)(ldst), 16, 0, 0)

// ---------------------------------------------------------------------------
// Embedding gather
// ---------------------------------------------------------------------------
__global__ void gather_kernel(const int* __restrict__ tokens,
                              const float* __restrict__ embed,
                              float* __restrict__ h) {
    int row = blockIdx.x;
    int t = tokens[row];
    const float4* src = (const float4*)(embed + (size_t)t * D_);
    float4* dst = (float4*)(h + (size_t)row * D_);
    dst[threadIdx.x] = src[threadIdx.x];
}

// ---------------------------------------------------------------------------
// fp32 -> bf16 bulk convert (row-major, no transpose). count % 2048 == 0.
// ---------------------------------------------------------------------------
__global__ __launch_bounds__(256) void cvt_kernel(const float* __restrict__ in,
                                                  bf16_t* __restrict__ out) {
    size_t i = ((size_t)blockIdx.x * 256 + threadIdx.x) * 8;
    float4 f0 = ((const float4*)(in + i))[0];
    float4 f1 = ((const float4*)(in + i))[1];
    bf16x8 ov;
    ov[0] = (bf16_t)f0.x; ov[1] = (bf16_t)f0.y;
    ov[2] = (bf16_t)f0.z; ov[3] = (bf16_t)f0.w;
    ov[4] = (bf16_t)f1.x; ov[5] = (bf16_t)f1.y;
    ov[6] = (bf16_t)f1.z; ov[7] = (bf16_t)f1.w;
    *(bf16x8*)(out + i) = ov;
}

// ---------------------------------------------------------------------------
// Bias concat: o[i][0:D) = a[i], o[i][D:2D) = b[i]
// ---------------------------------------------------------------------------
__global__ void bconcat_kernel(const float* __restrict__ a,
                               const float* __restrict__ b,
                               float* __restrict__ o) {
    int i = blockIdx.x, t = threadIdx.x;   // block 512
    o[(size_t)i * 2 * D_ + t]       = a[(size_t)i * D_ + t];
    o[(size_t)i * 2 * D_ + D_ + t]  = b[(size_t)i * D_ + t];
}

// ---------------------------------------------------------------------------
// LayerNorm over D=512; optional fp32 and bf16 outputs.
// ---------------------------------------------------------------------------
__global__ __launch_bounds__(256) void ln_kernel(const float* __restrict__ in,
                                                 const float* __restrict__ g,
                                                 const float* __restrict__ b,
                                                 float* __restrict__ outf,
                                                 bf16_t* __restrict__ outb) {
    int row = blockIdx.x, tid = threadIdx.x;
    const float* rp = in + (size_t)row * D_;
    float v0 = rp[tid], v1 = rp[tid + 256];
    float s = v0 + v1, q = v0 * v0 + v1 * v1;
#pragma unroll
    for (int o = 32; o > 0; o >>= 1) {
        s += __shfl_down(s, o, 64);
        q += __shfl_down(q, o, 64);
    }
    __shared__ float ss[4], sq[4];
    if ((tid & 63) == 0) { ss[tid >> 6] = s; sq[tid >> 6] = q; }
    __syncthreads();
    float ts = ss[0] + ss[1] + ss[2] + ss[3];
    float tq = sq[0] + sq[1] + sq[2] + sq[3];
    float mean = ts * (1.0f / D_);
    float var = tq * (1.0f / D_) - mean * mean;
    float rstd = rsqrtf(var + 1e-5f);
    float o0 = (v0 - mean) * rstd * g[tid] + b[tid];
    float o1 = (v1 - mean) * rstd * g[tid + 256] + b[tid + 256];
    if (outf) {
        outf[(size_t)row * D_ + tid]       = o0;
        outf[(size_t)row * D_ + tid + 256] = o1;
    }
    if (outb) {
        outb[(size_t)row * D_ + tid]       = (bf16_t)o0;
        outb[(size_t)row * D_ + tid + 256] = (bf16_t)o1;
    }
}

// ---------------------------------------------------------------------------
// Fused split-K sum + LayerNorm:
//   hnew = h + p0 + p1 + bias;  h = hnew
//   LN(hnew, g, b) -> outf (fp32, nullable), outb (bf16)
// One row per block, 256 threads. Same reduction as ln_kernel -> numerics
// identical to sumk followed by ln. All accesses coalesced.
// ---------------------------------------------------------------------------
__global__ __launch_bounds__(256) void sumk_ln_kernel(
    const float* __restrict__ p0, const float* __restrict__ p1,
    const float* __restrict__ bias, float* __restrict__ h,
    const float* __restrict__ g, const float* __restrict__ b,
    float* __restrict__ outf, bf16_t* __restrict__ outb) {
    int row = blockIdx.x, tid = threadIdx.x;
    size_t o = (size_t)row * D_;
    float v0 = h[o + tid]       + p0[o + tid]       + p1[o + tid]       + bias[tid];
    float v1 = h[o + tid + 256] + p0[o + tid + 256] + p1[o + tid + 256] + bias[tid + 256];
    h[o + tid]       = v0;
    h[o + tid + 256] = v1;
    float s = v0 + v1, q = v0 * v0 + v1 * v1;
#pragma unroll
    for (int of = 32; of > 0; of >>= 1) {
        s += __shfl_down(s, of, 64);
        q += __shfl_down(q, of, 64);
    }
    __shared__ float ss[4], sq[4];
    if ((tid & 63) == 0) { ss[tid >> 6] = s; sq[tid >> 6] = q; }
    __syncthreads();
    float ts = ss[0] + ss[1] + ss[2] + ss[3];
    float tq = sq[0] + sq[1] + sq[2] + sq[3];
    float mean = ts * (1.0f / D_);
    float var = tq * (1.0f / D_) - mean * mean;
    float rstd = rsqrtf(var + 1e-5f);
    float o0 = (v0 - mean) * rstd * g[tid] + b[tid];
    float o1 = (v1 - mean) * rstd * g[tid + 256] + b[tid + 256];
    if (outf) {
        outf[o + tid]       = o0;
        outf[o + tid + 256] = o1;
    }
    outb[o + tid]       = (bf16_t)o0;
    outb[o + tid + 256] = (bf16_t)o1;
}

// ---------------------------------------------------------------------------
// Transpose + fp32->bf16 convert: in fp32 [R][C-strided] -> out bf16 [.][R]
// grid (cols/32, R/32, Z), block 256
// ---------------------------------------------------------------------------
__global__ __launch_bounds__(256) void tconv_kernel(const float* __restrict__ in,
                                                    bf16_t* __restrict__ out,
                                                    int R, int C,
                                                    size_t inz, size_t outz) {
    __shared__ float t[32][33];
    const float* ip = in + (size_t)blockIdx.z * inz;
    bf16_t* op = out + (size_t)blockIdx.z * outz;
    int r0 = blockIdx.y * 32, c0 = blockIdx.x * 32;
    int tx = threadIdx.x & 31, ty = threadIdx.x >> 5;  // ty in [0,8)
#pragma unroll
    for (int rr = 0; rr < 4; ++rr)
        t[ty + rr * 8][tx] = ip[(size_t)(r0 + ty + rr * 8) * C + c0 + tx];
    __syncthreads();
#pragma unroll
    for (int rr = 0; rr < 4; ++rr)
        op[(size_t)(c0 + ty + rr * 8) * R + r0 + tx] = (bf16_t)t[tx][ty + rr * 8];
}

// ---------------------------------------------------------------------------
// MFMA bf16 GEMM: C[M,N] = epilogue(A[M,K] @ B^T[N,K])
//   BK=32 path: head (NBUF=3 measured best — structural ceiling ~216 us).
//   BK=64 path: layer GEMMs (r8 measured best; XOR-swizzled LDS).
// flags: 1 tanh, 2 gelu, 8 inv, 16 causal, 32 tanh-lo, 64 tri, 128 half-K.
// swz: bijective XCD-chunked block remap, m-fast within each n-panel chunk.
// ---------------------------------------------------------------------------
template<int BM, int BN, int NBUF, int BK, bool BF32>
__global__ __launch_bounds__(256) void mgemm(
    const bf16_t* __restrict__ A, const void* __restrict__ Bp,
    const float* __restrict__ bias, const float* __restrict__ res1,
    const float* __restrict__ res2, float* __restrict__ Cf,
    bf16_t* __restrict__ Cb, int M, int N, int Kd, int flags,
    long long strA, long long strB, long long strC, int swz) {
    __shared__ bf16_t sA[NBUF][BM * BK];
    __shared__ bf16_t sB[NBUF][BN * BK];
    const int tid = threadIdx.x;
    const int wave = tid >> 6, lane = tid & 63;
    const int lrow = lane & 15, quad = lane >> 4;
    int bx = blockIdx.x, by = blockIdx.y;
    if (swz) {
        int gx = gridDim.x, gy = gridDim.y;
        int nwg = gx * gy;
        int lid = by * gx + bx;
        int q = nwg >> 3, r = nwg & 7;
        int xcd = lid & 7, slot = lid >> 3;
        int base = (xcd < r) ? xcd * (q + 1) : r * (q + 1) + (xcd - r) * q;
        int nid = base + slot;       // contiguous chunk per XCD
        bx = nid / gy;               // n varies slowly
        by = nid - bx * gy;          // m fast within an n-panel
    }
    if ((flags & FLAG_TRI) && bx > by) return;   // strictly-upper: never read
    const int m0 = by * BM, n0 = bx * BN;
    const int z = blockIdx.z;
    A += (size_t)z * strA;
    const bf16_t* Bb = (const bf16_t*)Bp + (BF32 ? 0 : (size_t)z * strB);
    const float*  Bf = (const float*)Bp  + (BF32 ? (size_t)z * strB : 0);
    constexpr int TM = BM / 32, TN = BN / 32;  // 16x16 tiles per wave dim
    const int wm = (wave >> 1) * (BM / 2), wn = (wave & 1) * (BN / 2);
    f32x4 acc[TM][TN] = {};

    if constexpr (BF32) {
        // -------- fallback: single-buffered, fp32 B convert-staging --------
        for (int k0 = 0; k0 < Kd; k0 += 32) {
#pragma unroll
            for (int rb = 0; rb < BM / 64; ++rb) {
                int rowblk = wave * (BM / 64) + rb;
                int ml = rowblk * 16 + (lane >> 2);
                int qs = (lane & 3) ^ ((ml >> 1) & 3);
                GLDS(A + (size_t)(m0 + ml) * Kd + k0 + qs * 8, &sA[0][rowblk * 512]);
            }
#pragma unroll
            for (int rb = 0; rb < (BN * 4) / 256; ++rb) {
                int s = rb * 256 + tid;
                int nl = s >> 2, ql = s & 3;
                int qs = ql ^ ((nl >> 1) & 3);
                const float* src = Bf + (size_t)(n0 + nl) * Kd + k0 + qs * 8;
                float4 f0 = ((const float4*)src)[0];
                float4 f1 = ((const float4*)src)[1];
                bf16x8 ov;
                ov[0] = (bf16_t)f0.x; ov[1] = (bf16_t)f0.y;
                ov[2] = (bf16_t)f0.z; ov[3] = (bf16_t)f0.w;
                ov[4] = (bf16_t)f1.x; ov[5] = (bf16_t)f1.y;
                ov[6] = (bf16_t)f1.z; ov[7] = (bf16_t)f1.w;
                *(bf16x8*)(&sB[0][s * 8]) = ov;
            }
            __syncthreads();
            bf16x8 af[TM], bv[TN];
#pragma unroll
            for (int i = 0; i < TM; ++i) {
                int row = wm + i * 16 + lrow;
                af[i] = *(const bf16x8*)(&sA[0][(row * 4 + (quad ^ ((row >> 1) & 3))) * 8]);
            }
#pragma unroll
            for (int j = 0; j < TN; ++j) {
                int rown = wn + j * 16 + lrow;
                bv[j] = *(const bf16x8*)(&sB[0][(rown * 4 + (quad ^ ((rown >> 1) & 3))) * 8]);
            }
#pragma unroll
            for (int i = 0; i < TM; ++i)
#pragma unroll
                for (int j = 0; j < TN; ++j)
                    acc[i][j] = __builtin_amdgcn_mfma_f32_16x16x32_bf16(af[i], bv[j], acc[i][j], 0, 0, 0);
            __syncthreads();
        }
    } else if constexpr (BK == 64) {
        // -------- BK=64: 8-row GLDS groups, XOR-swizzled chunks --------
        int kend = Kd;
        if (flags & FLAG_CAUSAL) { int ke = m0 + BM; kend = ke < Kd ? ke : Kd; }
        if (flags & FLAG_HALFK) kend = Kd >> 1;
        const int nk = kend >> 6;
        constexpr int NLD = BM / 32 + BN / 32;   // GLDS per wave per stage
        auto stage = [&](int t, int buf) {
            const int k0 = t << 6;
#pragma unroll
            for (int rb = 0; rb < BM / 32; ++rb) {
                int r0 = (wave * (BM / 32) + rb) * 8;
                int row = r0 + (lane >> 3);
                int cs_ = (lane & 7) ^ (row & 7);
                GLDS(A + (size_t)(m0 + row) * Kd + k0 + cs_ * 8, &sA[buf][r0 * 64]);
            }
#pragma unroll
            for (int rb = 0; rb < BN / 32; ++rb) {
                int r0 = (wave * (BN / 32) + rb) * 8;
                int row = r0 + (lane >> 3);
                int cs_ = (lane & 7) ^ (row & 7);
                GLDS(Bb + (size_t)(n0 + row) * Kd + k0 + cs_ * 8, &sB[buf][r0 * 64]);
            }
        };
        auto compute = [&](int buf) {
            const bf16_t* sAc = sA[buf];
            const bf16_t* sBc = sB[buf];
            bf16x8 a0[TM], a1[TM], b0[TN], b1[TN];
#pragma unroll
            for (int i = 0; i < TM; ++i) {
                int row = wm + i * 16 + lrow;
                a0[i] = *(const bf16x8*)(sAc + row * 64 + ((quad       ^ (row & 7)) * 8));
                a1[i] = *(const bf16x8*)(sAc + row * 64 + (((4 | quad) ^ (row & 7)) * 8));
            }
#pragma unroll
            for (int j = 0; j < TN; ++j) {
                int rown = wn + j * 16 + lrow;
                b0[j] = *(const bf16x8*)(sBc + rown * 64 + ((quad       ^ (rown & 7)) * 8));
                b1[j] = *(const bf16x8*)(sBc + rown * 64 + (((4 | quad) ^ (rown & 7)) * 8));
            }
#pragma unroll
            for (int i = 0; i < TM; ++i)
#pragma unroll
                for (int j = 0; j < TN; ++j)
                    acc[i][j] = __builtin_amdgcn_mfma_f32_16x16x32_bf16(a0[i], b0[j], acc[i][j], 0, 0, 0);
#pragma unroll
            for (int i = 0; i < TM; ++i)
#pragma unroll
                for (int j = 0; j < TN; ++j)
                    acc[i][j] = __builtin_amdgcn_mfma_f32_16x16x32_bf16(a1[i], b1[j], acc[i][j], 0, 0, 0);
        };
        for (int t = 0; t < NBUF - 1 && t < nk; ++t) stage(t, t);
        int bcur = 0;
        for (int t = 0; t < nk; ++t) {
            const int nxt = t + NBUF - 1;
            if (nxt < nk) {
                int bn = bcur + NBUF - 1; if (bn >= NBUF) bn -= NBUF;
                stage(nxt, bn);
            }
            const int last = (nxt < nk) ? nxt : nk - 1;
            const int ahead = last - t;
            if (ahead >= 2)      asm volatile("s_waitcnt vmcnt(%0)" :: "n"(2 * NLD) : "memory");
            else if (ahead == 1) asm volatile("s_waitcnt vmcnt(%0)" :: "n"(1 * NLD) : "memory");
            else                 asm volatile("s_waitcnt vmcnt(0)" ::: "memory");
            __builtin_amdgcn_s_barrier();
            compute(bcur);
            asm volatile("s_waitcnt lgkmcnt(0)" ::: "memory");
            __builtin_amdgcn_s_barrier();
            bcur = (bcur + 1 == NBUF) ? 0 : bcur + 1;
        }
    } else {
        // -------- BK=32 (head) --------
        int kend = Kd;
        if (flags & FLAG_CAUSAL) { int ke = m0 + BM; kend = ke < Kd ? ke : Kd; }
        if (flags & FLAG_HALFK) kend = Kd >> 1;
        const int nk = kend >> 5;
        constexpr int NLD = BM / 64 + BN / 64;   // GLDS ops per wave per stage
        auto stage = [&](int t, int buf) {
            const int k0 = t << 5;
#pragma unroll
            for (int rb = 0; rb < BM / 64; ++rb) {
                int rowblk = wave * (BM / 64) + rb;
                int ml = rowblk * 16 + (lane >> 2);
                int qs = (lane & 3) ^ ((ml >> 1) & 3);
                GLDS(A + (size_t)(m0 + ml) * Kd + k0 + qs * 8, &sA[buf][rowblk * 512]);
            }
#pragma unroll
            for (int rb = 0; rb < BN / 64; ++rb) {
                int rowblk = wave * (BN / 64) + rb;
                int nl = rowblk * 16 + (lane >> 2);
                int qs = (lane & 3) ^ ((nl >> 1) & 3);
                GLDS(Bb + (size_t)(n0 + nl) * Kd + k0 + qs * 8, &sB[buf][rowblk * 512]);
            }
        };
        auto compute = [&](int buf) {
            const bf16_t* sAc = sA[buf];
            const bf16_t* sBc = sB[buf];
            bf16x8 af[TM], bv[TN];
#pragma unroll
            for (int i = 0; i < TM; ++i) {
                int row = wm + i * 16 + lrow;
                af[i] = *(const bf16x8*)(sAc + (row * 4 + (quad ^ ((row >> 1) & 3))) * 8);
            }
#pragma unroll
            for (int j = 0; j < TN; ++j) {
                int rown = wn + j * 16 + lrow;
                bv[j] = *(const bf16x8*)(sBc + (rown * 4 + (quad ^ ((rown >> 1) & 3))) * 8);
            }
#pragma unroll
            for (int i = 0; i < TM; ++i)
#pragma unroll
                for (int j = 0; j < TN; ++j)
                    acc[i][j] = __builtin_amdgcn_mfma_f32_16x16x32_bf16(af[i], bv[j], acc[i][j], 0, 0, 0);
        };
        if constexpr (NBUF == 2) {
            stage(0, 0);
            int cur = 0;
            for (int t = 0; t < nk; ++t) {
                if (t + 1 < nk) {
                    stage(t + 1, cur ^ 1);
                    asm volatile("s_waitcnt vmcnt(%0)" :: "n"(NLD) : "memory");
                } else {
                    asm volatile("s_waitcnt vmcnt(0)" ::: "memory");
                }
                __builtin_amdgcn_s_barrier();
                compute(cur);
                asm volatile("s_waitcnt lgkmcnt(0)" ::: "memory");
                __builtin_amdgcn_s_barrier();
                cur ^= 1;
            }
        } else {
            // NBUF=3: triple buffer (explicit rotation), 2 stages in flight
            stage(0, 0);
            if (nk > 1) stage(1, 1);
            int b0 = 0;
            for (int t = 0; t < nk; ++t) {
                const int nxt = t + 2;
                if (nxt < nk) {
                    int bn = b0 + 2; if (bn >= 3) bn -= 3;
                    stage(nxt, bn);
                }
                const int last = (nxt < nk) ? nxt : nk - 1;
                const int ahead = last - t;
                if (ahead >= 2)      asm volatile("s_waitcnt vmcnt(%0)" :: "n"(2 * NLD) : "memory");
                else if (ahead == 1) asm volatile("s_waitcnt vmcnt(%0)" :: "n"(1 * NLD) : "memory");
                else                 asm volatile("s_waitcnt vmcnt(0)" ::: "memory");
                __builtin_amdgcn_s_barrier();
                compute(b0);
                asm volatile("s_waitcnt lgkmcnt(0)" ::: "memory");
                __builtin_amdgcn_s_barrier();
                b0 = (b0 == 2) ? 0 : b0 + 1;
            }
        }
    }

    // --- epilogue: C/D layout col=lane&15, row=quad*4+reg ---
    const size_t zo = (size_t)z * strC;
#pragma unroll
    for (int i = 0; i < TM; ++i) {
#pragma unroll
        for (int reg = 0; reg < 4; ++reg) {
            int m = m0 + wm + i * 16 + quad * 4 + reg;
            float rs = (flags & FLAG_INV) ? rsqrtf((float)(m + 1) * (float)K_) : 1.0f;
#pragma unroll
            for (int j = 0; j < TN; ++j) {
                int n = n0 + wn + j * 16 + lrow;
                float vv = acc[i][j][reg];
                if (bias) vv += bias[n];
                vv *= rs;
                if (flags & FLAG_TANH) vv = tanhf(vv);
                else if (flags & FLAG_GELU) vv = 0.5f * vv * (1.0f + erff(vv * 0.7071067811865476f));
                else if (flags & FLAG_TANHLO) { if (n < D_) vv = tanhf(vv); }
                if ((flags & FLAG_TRI) && n > m) vv = 0.f;
                size_t idx = zo + (size_t)m * N + n;
                if (res1) vv += res1[idx];
                if (res2) vv += res2[idx];
                if (Cf) Cf[idx] = vv;
                if (Cb) Cb[idx] = (bf16_t)vv;
            }
        }
    }
}

// ---------------------------------------------------------------------------
// Phase kernel: 4 rows per block (256 threads). Writes bf16 [cos|sin] into
// csb [row][64]. t1 rows strided 2*D (fused t1|v buffer).
// ---------------------------------------------------------------------------
__global__ __launch_bounds__(256) void phase_kernel(const float* __restrict__ t1,
                             const float* __restrict__ w2,
                             const float* __restrict__ b2,
                             const float* __restrict__ ps,
                             const float* __restrict__ cs,
                             int layer,
                             bf16_t* __restrict__ csb) {
    int tid = threadIdx.x;
    int rl = tid >> 6;                   // 0..3: row within block
    int k = tid & 31, hh = (tid >> 5) & 1;
    int row = blockIdx.x * 4 + rl;
    int l = row & (L_ - 1);
    const float* tr = t1 + (size_t)row * (2 * D_);
    float acc = 0.f;
    for (int d = hh * 256; d < hh * 256 + 256; ++d)
        acc = fmaf(tr[d], w2[d * K_ + k], acc);
    __shared__ float red[256];
    red[tid] = acc;
    __syncthreads();
    if (hh == 0) {
        float zz = red[rl * 64 + k] + red[rl * 64 + 32 + k] + b2[k];
        float cp = tanhf(zz) * 3.14159265358979323846f;
        float freq = expf(-(float)k * (9.210340371976184f / (float)K_));
        float tp = ps[layer] * (float)l * freq + cs[layer] * cp;
        csb[(size_t)row * 64 + k]      = (bf16_t)cosf(tp);
        csb[(size_t)row * 64 + 32 + k] = (bf16_t)sinf(tp);
    }
}

// ---------------------------------------------------------------------------
extern "C" void kernel_launch(void* const* d_in, const int* in_sizes, int n_in,
                              void* d_out, int out_size, void* d_ws, size_t ws_size,
                              hipStream_t stream) {
    const int*   tokens        = (const int*)d_in[0];
    const float* embed         = (const float*)d_in[1];
    const float* ln1_g         = (const float*)d_in[2];
    const float* ln1_b         = (const float*)d_in[3];
    const float* cp_w1         = (const float*)d_in[4];
    const float* cp_b1         = (const float*)d_in[5];
    const float* cp_w2         = (const float*)d_in[6];
    const float* cp_b2         = (const float*)d_in[7];
    const float* pos_scale     = (const float*)d_in[8];
    const float* content_scale = (const float*)d_in[9];
    const float* val_w         = (const float*)d_in[10];
    const float* val_b         = (const float*)d_in[11];
    const float* oln_g         = (const float*)d_in[12];
    const float* oln_b         = (const float*)d_in[13];
    const float* out_w         = (const float*)d_in[14];
    const float* out_b         = (const float*)d_in[15];
    const float* ln2_g         = (const float*)d_in[16];
    const float* ln2_b         = (const float*)d_in[17];
    const float* ffn_w1        = (const float*)d_in[18];
    const float* ffn_b1        = (const float*)d_in[19];
    const float* ffn_w2        = (const float*)d_in[20];
    const float* ffn_b2        = (const float*)d_in[21];
    const float* no_g          = (const float*)d_in[22];
    const float* no_b          = (const float*)d_in[23];
    const float* head_b        = (const float*)d_in[24];
    float* out = (float*)d_out;

    // Scratch in d_out (dead before head GEMM writes). hn_bf + emb_bf in d_ws.
    float* h   = out;                        // MR*D fp32
    float* x   = h  + (size_t)MR_ * D_;      // MR*D fp32
    float* t1v = x  + (size_t)MR_ * D_;      // MR*2D fp32 (t1 | v fused)
    float* r   = t1v + (size_t)MR_ * 2 * D_; // MR*D fp32
    bf16_t* x_bf  = (bf16_t*)(r + (size_t)MR_ * D_);
    bf16_t* r_bf  = x_bf  + (size_t)MR_ * D_;
    bf16_t* y_bf  = r_bf  + (size_t)MR_ * D_;
    bf16_t* ff_bf = y_bf  + (size_t)MR_ * D_;          // MR*FF
    bf16_t* sc_bf = ff_bf + (size_t)MR_ * FF_;         // B*L*L
    bf16_t* vT_bf = sc_bf + (size_t)B_ * L_ * L_;      // B*D*L
    bf16_t* csb   = vT_bf + (size_t)B_ * D_ * L_;      // MR*64 (cos|sin bf16)
    bf16_t* wvT   = csb   + (size_t)MR_ * 64;          // NL*2*D*D (w1T|vwT per layer)
    bf16_t* owT   = wvT   + (size_t)NL_ * 2 * D_ * D_;
    bf16_t* f1T   = owT   + (size_t)NL_ * D_ * D_;     // NL*FF*D
    bf16_t* f2T   = f1T   + (size_t)NL_ * FF_ * D_;    // NL*D*FF
    float*  b1v   = (float*)(f2T + (size_t)NL_ * D_ * FF_); // NL*2D fp32
    float*  pK    = b1v + (size_t)NL_ * 2 * D_;        // 2*MR*D fp32 split-K partials
    bf16_t* hn_bf = (bf16_t*)d_ws;                     // MR*D (2 MB)
    bf16_t* emb_bf = hn_bf + (size_t)MR_ * D_;         // V*D bf16 (32.8 MB)
    const bool big_ws =
        ws_size >= ((size_t)MR_ * D_ + (size_t)V_ * D_) * sizeof(bf16_t);

    gather_kernel<<<MR_, 128, 0, stream>>>(tokens, embed, h);

    // Pre-transpose + convert all weights to bf16 [N][K]
    // Fused t1|v weight: layer i rows [0,D) = cp_w1^T, rows [D,2D) = val_w^T
    tconv_kernel<<<dim3(16, 16, NL_), 256, 0, stream>>>(cp_w1, wvT, D_, D_, (size_t)D_ * D_, (size_t)2 * D_ * D_);
    tconv_kernel<<<dim3(16, 16, NL_), 256, 0, stream>>>(val_w, wvT + (size_t)D_ * D_, D_, D_, (size_t)D_ * D_, (size_t)2 * D_ * D_);
    bconcat_kernel<<<NL_, 512, 0, stream>>>(cp_b1, val_b, b1v);
    tconv_kernel<<<dim3(16, 16, NL_), 256, 0, stream>>>(out_w, owT, D_, D_, (size_t)D_ * D_, (size_t)D_ * D_);
    tconv_kernel<<<dim3(64, 16, NL_), 256, 0, stream>>>(ffn_w1, f1T, D_, FF_, (size_t)D_ * FF_, (size_t)D_ * FF_);
    tconv_kernel<<<dim3(16, 64, NL_), 256, 0, stream>>>(ffn_w2, f2T, FF_, D_, (size_t)FF_ * D_, (size_t)FF_ * D_);
    // embed is already [N=V][K=D]: straight convert to bf16 for the head GEMM
    if (big_ws)
        cvt_kernel<<<(V_ * D_) / 2048, 256, 0, stream>>>(embed, emb_bf);

    for (int i = 0; i < NL_; ++i) {
        // x = LN(h): explicit only for layer 0 (fused into prev sumk_ln after)
        if (i == 0)
            ln_kernel<<<MR_, 256, 0, stream>>>(h, ln1_g, ln1_b, x, x_bf);
        // t1v = [tanh(x @ cp_w1 + cp_b1) | x @ val_w + val_b]  (fused, N=1024)
        mgemm<64, 64, 3, 64, false><<<dim3(16, 32, 1), 256, 0, stream>>>(
            x_bf, wvT + (size_t)i * 2 * D_ * D_, b1v + (size_t)i * 2 * D_,
            nullptr, nullptr, t1v, nullptr, MR_, 2 * D_, D_, FLAG_TANHLO, 0, 0, 0, 1);
        // csb = bf16 [cos|sin] phases (reads t1 = cols [0,D) of t1v)
        phase_kernel<<<MR_ / 4, 256, 0, stream>>>(
            t1v, cp_w2 + (size_t)i * D_ * K_, cp_b2 + i * K_,
            pos_scale, content_scale, i, csb);
        // vT (bf16, [b][D][L]) from cols [D,2D) of t1v — coalesced LDS transpose
        tconv_kernel<<<dim3(16, 32, B_), 256, 0, stream>>>(
            t1v + D_, vT_bf, L_, 2 * D_, (size_t)L_ * 2 * D_, (size_t)D_ * L_);
        // scores = tri(CS @ CS^T)  (K=64 GEMM; lower-triangle blocks only)
        mgemm<64, 64, 3, 64, false><<<dim3(L_ / 64, L_ / 64, B_), 256, 0, stream>>>(
            csb, csb, nullptr, nullptr, nullptr, nullptr, sc_bf,
            L_, L_, 64, FLAG_TRI,
            (long long)L_ * 64, (long long)L_ * 64, (long long)L_ * L_, 0);
        // r = (A @ v) * inv_norm  (batched over z; causal K-loop)
        mgemm<64, 64, 3, 64, false><<<dim3(8, 16, B_), 256, 0, stream>>>(
            sc_bf, vT_bf, nullptr, nullptr, nullptr, r, nullptr,
            L_, D_, L_, FLAG_INV | FLAG_CAUSAL,
            (long long)L_ * L_, (long long)D_ * L_, (long long)L_ * D_, 1);
        // r_bf = LN(r)
        ln_kernel<<<MR_, 256, 0, stream>>>(r, oln_g + i * D_, oln_b + i * D_, nullptr, r_bf);
        // h = h + x + (r_bf @ out_w + out_b)
        mgemm<64, 64, 3, 64, false><<<dim3(8, 32, 1), 256, 0, stream>>>(
            r_bf, owT + (size_t)i * D_ * D_, out_b + i * D_,
            h, x, h, nullptr, MR_, D_, D_, 0, 0, 0, 0, 1);
        // y_bf = LN(h)
        ln_kernel<<<MR_, 256, 0, stream>>>(h, ln2_g + i * D_, ln2_b + i * D_, nullptr, y_bf);
        // ff_bf = gelu(y @ ffn_w1 + b1)  (bf16 only)
        mgemm<128, 128, 3, 64, false><<<dim3(16, 16, 1), 256, 0, stream>>>(
            y_bf, f1T + (size_t)i * FF_ * D_, ffn_b1 + i * FF_,
            nullptr, nullptr, nullptr, ff_bf, MR_, FF_, D_, FLAG_GELU, 0, 0, 0, 1);
        // ffn2 split-K=2: pK[z] = ff[:, z*FF/2:(z+1)*FF/2] @ f2T[z-chunk]
        mgemm<64, 64, 3, 64, false><<<dim3(8, 32, 2), 256, 0, stream>>>(
            ff_bf, f2T + (size_t)i * D_ * FF_, nullptr,
            nullptr, nullptr, pK, nullptr, MR_, D_, FF_, FLAG_HALFK,
            (long long)(FF_ / 2), (long long)(FF_ / 2), (long long)MR_ * D_, 1);
        // h += pK0 + pK1 + ffn_b2, fused with next LN:
        //   layers 0..NL-2 -> next layer's ln1 (x, x_bf); last -> final LN (hn_bf)
        if (i < NL_ - 1) {
            sumk_ln_kernel<<<MR_, 256, 0, stream>>>(
                pK, pK + (size_t)MR_ * D_, ffn_b2 + i * D_, h,
                ln1_g + (i + 1) * D_, ln1_b + (i + 1) * D_, x, x_bf);
        } else {
            sumk_ln_kernel<<<MR_, 256, 0, stream>>>(
                pK, pK + (size_t)MR_ * D_, ffn_b2 + i * D_, h,
                no_g, no_b, nullptr, hn_bf);
        }
    }

    // out = hn @ embed^T + head_b
    if (big_ws) {
        mgemm<128, 128, 3, 32, false><<<dim3(V_ / 128, MR_ / 128, 1), 256, 0, stream>>>(
            hn_bf, emb_bf, head_b, nullptr, nullptr, out, nullptr,
            MR_, V_, D_, 0, 0, 0, 0, 1);
    } else {
        mgemm<128, 128, 1, 32, true><<<dim3(V_ / 128, MR_ / 128, 1), 256, 0, stream>>>(
            hn_bf, embed, head_b, nullptr, nullptr, out, nullptr,
            MR_, V_, D_, 0, 0, 0, 0, 1);
    }
}

// Round 11
// 1317.613 us; speedup vs baseline: 1.0926x; 1.0509x over previous
//
#include <hip/hip_runtime.h>
#include <hip/hip_bf16.h>
#include <math.h>

// Problem constants
#define V_  32000
#define D_  512
#define NL_ 4
#define K_  32
#define B_  2
#define L_  1024
#define FF_ 2048
#define MR_ (B_ * L_)   // 2048 total rows

typedef __bf16 bf16_t;
typedef __bf16 bf16x8 __attribute__((ext_vector_type(8)));
typedef float  f32x4  __attribute__((ext_vector_type(4)));

#define FLAG_TANH   1
#define FLAG_GELU   2
#define FLAG_INV    8
#define FLAG_CAUSAL 16
#define FLAG_TANHLO 32   // tanh applied only to columns n < D_ (fused t1|v GEMM)
#define FLAG_TRI    64   // triangular score GEMM: skip bx>by blocks, zero n>m
#define FLAG_HALFK  128  // split-K: this dispatch covers Kd/2 (z selects chunk)

// async 16B global->LDS (wave-uniform LDS base + lane*16)
#define GLDS(gsrc, ldst) \
  __builtin_amdgcn_global_load_lds( \
      (const __attribute__((address_space(1))) unsigned int*)(const void*)(gsrc), \
      (__attribute__((address_space(3))) unsigned int*)(void*)(ldst), 16, 0, 0)

// ---------------------------------------------------------------------------
// Embedding gather
// ---------------------------------------------------------------------------
__global__ void gather_kernel(const int* __restrict__ tokens,
                              const float* __restrict__ embed,
                              float* __restrict__ h) {
    int row = blockIdx.x;
    int t = tokens[row];
    const float4* src = (const float4*)(embed + (size_t)t * D_);
    float4* dst = (float4*)(h + (size_t)row * D_);
    dst[threadIdx.x] = src[threadIdx.x];
}

// ---------------------------------------------------------------------------
// fp32 -> bf16 bulk convert (row-major, no transpose). count % 2048 == 0.
// ---------------------------------------------------------------------------
__global__ __launch_bounds__(256) void cvt_kernel(const float* __restrict__ in,
                                                  bf16_t* __restrict__ out) {
    size_t i = ((size_t)blockIdx.x * 256 + threadIdx.x) * 8;
    float4 f0 = ((const float4*)(in + i))[0];
    float4 f1 = ((const float4*)(in + i))[1];
    bf16x8 ov;
    ov[0] = (bf16_t)f0.x; ov[1] = (bf16_t)f0.y;
    ov[2] = (bf16_t)f0.z; ov[3] = (bf16_t)f0.w;
    ov[4] = (bf16_t)f1.x; ov[5] = (bf16_t)f1.y;
    ov[6] = (bf16_t)f1.z; ov[7] = (bf16_t)f1.w;
    *(bf16x8*)(out + i) = ov;
}

// ---------------------------------------------------------------------------
// Bias concat: o[i][0:D) = a[i], o[i][D:2D) = b[i]
// ---------------------------------------------------------------------------
__global__ void bconcat_kernel(const float* __restrict__ a,
                               const float* __restrict__ b,
                               float* __restrict__ o) {
    int i = blockIdx.x, t = threadIdx.x;   // block 512
    o[(size_t)i * 2 * D_ + t]       = a[(size_t)i * D_ + t];
    o[(size_t)i * 2 * D_ + D_ + t]  = b[(size_t)i * D_ + t];
}

// ---------------------------------------------------------------------------
// LayerNorm over D=512; optional fp32 and bf16 outputs.
// ---------------------------------------------------------------------------
__global__ __launch_bounds__(256) void ln_kernel(const float* __restrict__ in,
                                                 const float* __restrict__ g,
                                                 const float* __restrict__ b,
                                                 float* __restrict__ outf,
                                                 bf16_t* __restrict__ outb) {
    int row = blockIdx.x, tid = threadIdx.x;
    const float* rp = in + (size_t)row * D_;
    float v0 = rp[tid], v1 = rp[tid + 256];
    float s = v0 + v1, q = v0 * v0 + v1 * v1;
#pragma unroll
    for (int o = 32; o > 0; o >>= 1) {
        s += __shfl_down(s, o, 64);
        q += __shfl_down(q, o, 64);
    }
    __shared__ float ss[4], sq[4];
    if ((tid & 63) == 0) { ss[tid >> 6] = s; sq[tid >> 6] = q; }
    __syncthreads();
    float ts = ss[0] + ss[1] + ss[2] + ss[3];
    float tq = sq[0] + sq[1] + sq[2] + sq[3];
    float mean = ts * (1.0f / D_);
    float var = tq * (1.0f / D_) - mean * mean;
    float rstd = rsqrtf(var + 1e-5f);
    float o0 = (v0 - mean) * rstd * g[tid] + b[tid];
    float o1 = (v1 - mean) * rstd * g[tid + 256] + b[tid + 256];
    if (outf) {
        outf[(size_t)row * D_ + tid]       = o0;
        outf[(size_t)row * D_ + tid + 256] = o1;
    }
    if (outb) {
        outb[(size_t)row * D_ + tid]       = (bf16_t)o0;
        outb[(size_t)row * D_ + tid + 256] = (bf16_t)o1;
    }
}

// ---------------------------------------------------------------------------
// Fused split-K sum + LayerNorm:
//   hnew = h + p0 + p1 + bias;  h = hnew
//   LN(hnew, g, b) -> outf (fp32, nullable), outb (bf16)
// One row per block, 256 threads. Same reduction as ln_kernel -> numerics
// identical to sumk followed by ln. All accesses coalesced.
// ---------------------------------------------------------------------------
__global__ __launch_bounds__(256) void sumk_ln_kernel(
    const float* __restrict__ p0, const float* __restrict__ p1,
    const float* __restrict__ bias, float* __restrict__ h,
    const float* __restrict__ g, const float* __restrict__ b,
    float* __restrict__ outf, bf16_t* __restrict__ outb) {
    int row = blockIdx.x, tid = threadIdx.x;
    size_t o = (size_t)row * D_;
    float v0 = h[o + tid]       + p0[o + tid]       + p1[o + tid]       + bias[tid];
    float v1 = h[o + tid + 256] + p0[o + tid + 256] + p1[o + tid + 256] + bias[tid + 256];
    h[o + tid]       = v0;
    h[o + tid + 256] = v1;
    float s = v0 + v1, q = v0 * v0 + v1 * v1;
#pragma unroll
    for (int of = 32; of > 0; of >>= 1) {
        s += __shfl_down(s, of, 64);
        q += __shfl_down(q, of, 64);
    }
    __shared__ float ss[4], sq[4];
    if ((tid & 63) == 0) { ss[tid >> 6] = s; sq[tid >> 6] = q; }
    __syncthreads();
    float ts = ss[0] + ss[1] + ss[2] + ss[3];
    float tq = sq[0] + sq[1] + sq[2] + sq[3];
    float mean = ts * (1.0f / D_);
    float var = tq * (1.0f / D_) - mean * mean;
    float rstd = rsqrtf(var + 1e-5f);
    float o0 = (v0 - mean) * rstd * g[tid] + b[tid];
    float o1 = (v1 - mean) * rstd * g[tid + 256] + b[tid + 256];
    if (outf) {
        outf[o + tid]       = o0;
        outf[o + tid + 256] = o1;
    }
    outb[o + tid]       = (bf16_t)o0;
    outb[o + tid + 256] = (bf16_t)o1;
}

// ---------------------------------------------------------------------------
// Transpose + fp32->bf16 convert: in fp32 [R][C-strided] -> out bf16 [.][R]
// grid (cols/32, R/32, Z), block 256
// ---------------------------------------------------------------------------
__global__ __launch_bounds__(256) void tconv_kernel(const float* __restrict__ in,
                                                    bf16_t* __restrict__ out,
                                                    int R, int C,
                                                    size_t inz, size_t outz) {
    __shared__ float t[32][33];
    const float* ip = in + (size_t)blockIdx.z * inz;
    bf16_t* op = out + (size_t)blockIdx.z * outz;
    int r0 = blockIdx.y * 32, c0 = blockIdx.x * 32;
    int tx = threadIdx.x & 31, ty = threadIdx.x >> 5;  // ty in [0,8)
#pragma unroll
    for (int rr = 0; rr < 4; ++rr)
        t[ty + rr * 8][tx] = ip[(size_t)(r0 + ty + rr * 8) * C + c0 + tx];
    __syncthreads();
#pragma unroll
    for (int rr = 0; rr < 4; ++rr)
        op[(size_t)(c0 + ty + rr * 8) * R + r0 + tx] = (bf16_t)t[tx][ty + rr * 8];
}

// ---------------------------------------------------------------------------
// MFMA bf16 GEMM: C[M,N] = epilogue(A[M,K] @ B^T[N,K])
//   BK=32 path: head. BM=128,BN=64,NBUF=3 -> 36 KB LDS -> 4 blocks/CU
//     (r10 diagnosis: head latency-bound at 2.4 blocks/CU; TLP is the knob).
//   BK=64 path: layer GEMMs (r8 measured best; XOR-swizzled LDS).
// flags: 1 tanh, 2 gelu, 8 inv, 16 causal, 32 tanh-lo, 64 tri, 128 half-K.
// swz: bijective XCD-chunked block remap, m-fast within each n-panel chunk.
// ---------------------------------------------------------------------------
template<int BM, int BN, int NBUF, int BK, bool BF32>
__global__ __launch_bounds__(256) void mgemm(
    const bf16_t* __restrict__ A, const void* __restrict__ Bp,
    const float* __restrict__ bias, const float* __restrict__ res1,
    const float* __restrict__ res2, float* __restrict__ Cf,
    bf16_t* __restrict__ Cb, int M, int N, int Kd, int flags,
    long long strA, long long strB, long long strC, int swz) {
    __shared__ bf16_t sA[NBUF][BM * BK];
    __shared__ bf16_t sB[NBUF][BN * BK];
    const int tid = threadIdx.x;
    const int wave = tid >> 6, lane = tid & 63;
    const int lrow = lane & 15, quad = lane >> 4;
    int bx = blockIdx.x, by = blockIdx.y;
    if (swz) {
        int gx = gridDim.x, gy = gridDim.y;
        int nwg = gx * gy;
        int lid = by * gx + bx;
        int q = nwg >> 3, r = nwg & 7;
        int xcd = lid & 7, slot = lid >> 3;
        int base = (xcd < r) ? xcd * (q + 1) : r * (q + 1) + (xcd - r) * q;
        int nid = base + slot;       // contiguous chunk per XCD
        bx = nid / gy;               // n varies slowly
        by = nid - bx * gy;          // m fast within an n-panel
    }
    if ((flags & FLAG_TRI) && bx > by) return;   // strictly-upper: never read
    const int m0 = by * BM, n0 = bx * BN;
    const int z = blockIdx.z;
    A += (size_t)z * strA;
    const bf16_t* Bb = (const bf16_t*)Bp + (BF32 ? 0 : (size_t)z * strB);
    const float*  Bf = (const float*)Bp  + (BF32 ? (size_t)z * strB : 0);
    constexpr int TM = BM / 32, TN = BN / 32;  // 16x16 tiles per wave dim
    const int wm = (wave >> 1) * (BM / 2), wn = (wave & 1) * (BN / 2);
    f32x4 acc[TM][TN] = {};

    if constexpr (BF32) {
        // -------- fallback: single-buffered, fp32 B convert-staging --------
        for (int k0 = 0; k0 < Kd; k0 += 32) {
#pragma unroll
            for (int rb = 0; rb < BM / 64; ++rb) {
                int rowblk = wave * (BM / 64) + rb;
                int ml = rowblk * 16 + (lane >> 2);
                int qs = (lane & 3) ^ ((ml >> 1) & 3);
                GLDS(A + (size_t)(m0 + ml) * Kd + k0 + qs * 8, &sA[0][rowblk * 512]);
            }
#pragma unroll
            for (int rb = 0; rb < (BN * 4) / 256; ++rb) {
                int s = rb * 256 + tid;
                int nl = s >> 2, ql = s & 3;
                int qs = ql ^ ((nl >> 1) & 3);
                const float* src = Bf + (size_t)(n0 + nl) * Kd + k0 + qs * 8;
                float4 f0 = ((const float4*)src)[0];
                float4 f1 = ((const float4*)src)[1];
                bf16x8 ov;
                ov[0] = (bf16_t)f0.x; ov[1] = (bf16_t)f0.y;
                ov[2] = (bf16_t)f0.z; ov[3] = (bf16_t)f0.w;
                ov[4] = (bf16_t)f1.x; ov[5] = (bf16_t)f1.y;
                ov[6] = (bf16_t)f1.z; ov[7] = (bf16_t)f1.w;
                *(bf16x8*)(&sB[0][s * 8]) = ov;
            }
            __syncthreads();
            bf16x8 af[TM], bv[TN];
#pragma unroll
            for (int i = 0; i < TM; ++i) {
                int row = wm + i * 16 + lrow;
                af[i] = *(const bf16x8*)(&sA[0][(row * 4 + (quad ^ ((row >> 1) & 3))) * 8]);
            }
#pragma unroll
            for (int j = 0; j < TN; ++j) {
                int rown = wn + j * 16 + lrow;
                bv[j] = *(const bf16x8*)(&sB[0][(rown * 4 + (quad ^ ((rown >> 1) & 3))) * 8]);
            }
#pragma unroll
            for (int i = 0; i < TM; ++i)
#pragma unroll
                for (int j = 0; j < TN; ++j)
                    acc[i][j] = __builtin_amdgcn_mfma_f32_16x16x32_bf16(af[i], bv[j], acc[i][j], 0, 0, 0);
            __syncthreads();
        }
    } else if constexpr (BK == 64) {
        // -------- BK=64: 8-row GLDS groups, XOR-swizzled chunks --------
        int kend = Kd;
        if (flags & FLAG_CAUSAL) { int ke = m0 + BM; kend = ke < Kd ? ke : Kd; }
        if (flags & FLAG_HALFK) kend = Kd >> 1;
        const int nk = kend >> 6;
        constexpr int NLD = BM / 32 + BN / 32;   // GLDS per wave per stage
        auto stage = [&](int t, int buf) {
            const int k0 = t << 6;
#pragma unroll
            for (int rb = 0; rb < BM / 32; ++rb) {
                int r0 = (wave * (BM / 32) + rb) * 8;
                int row = r0 + (lane >> 3);
                int cs_ = (lane & 7) ^ (row & 7);
                GLDS(A + (size_t)(m0 + row) * Kd + k0 + cs_ * 8, &sA[buf][r0 * 64]);
            }
#pragma unroll
            for (int rb = 0; rb < BN / 32; ++rb) {
                int r0 = (wave * (BN / 32) + rb) * 8;
                int row = r0 + (lane >> 3);
                int cs_ = (lane & 7) ^ (row & 7);
                GLDS(Bb + (size_t)(n0 + row) * Kd + k0 + cs_ * 8, &sB[buf][r0 * 64]);
            }
        };
        auto compute = [&](int buf) {
            const bf16_t* sAc = sA[buf];
            const bf16_t* sBc = sB[buf];
            bf16x8 a0[TM], a1[TM], b0[TN], b1[TN];
#pragma unroll
            for (int i = 0; i < TM; ++i) {
                int row = wm + i * 16 + lrow;
                a0[i] = *(const bf16x8*)(sAc + row * 64 + ((quad       ^ (row & 7)) * 8));
                a1[i] = *(const bf16x8*)(sAc + row * 64 + (((4 | quad) ^ (row & 7)) * 8));
            }
#pragma unroll
            for (int j = 0; j < TN; ++j) {
                int rown = wn + j * 16 + lrow;
                b0[j] = *(const bf16x8*)(sBc + rown * 64 + ((quad       ^ (rown & 7)) * 8));
                b1[j] = *(const bf16x8*)(sBc + rown * 64 + (((4 | quad) ^ (rown & 7)) * 8));
            }
#pragma unroll
            for (int i = 0; i < TM; ++i)
#pragma unroll
                for (int j = 0; j < TN; ++j)
                    acc[i][j] = __builtin_amdgcn_mfma_f32_16x16x32_bf16(a0[i], b0[j], acc[i][j], 0, 0, 0);
#pragma unroll
            for (int i = 0; i < TM; ++i)
#pragma unroll
                for (int j = 0; j < TN; ++j)
                    acc[i][j] = __builtin_amdgcn_mfma_f32_16x16x32_bf16(a1[i], b1[j], acc[i][j], 0, 0, 0);
        };
        for (int t = 0; t < NBUF - 1 && t < nk; ++t) stage(t, t);
        int bcur = 0;
        for (int t = 0; t < nk; ++t) {
            const int nxt = t + NBUF - 1;
            if (nxt < nk) {
                int bn = bcur + NBUF - 1; if (bn >= NBUF) bn -= NBUF;
                stage(nxt, bn);
            }
            const int last = (nxt < nk) ? nxt : nk - 1;
            const int ahead = last - t;
            if (ahead >= 2)      asm volatile("s_waitcnt vmcnt(%0)" :: "n"(2 * NLD) : "memory");
            else if (ahead == 1) asm volatile("s_waitcnt vmcnt(%0)" :: "n"(1 * NLD) : "memory");
            else                 asm volatile("s_waitcnt vmcnt(0)" ::: "memory");
            __builtin_amdgcn_s_barrier();
            compute(bcur);
            asm volatile("s_waitcnt lgkmcnt(0)" ::: "memory");
            __builtin_amdgcn_s_barrier();
            bcur = (bcur + 1 == NBUF) ? 0 : bcur + 1;
        }
    } else {
        // -------- BK=32 (head) --------
        int kend = Kd;
        if (flags & FLAG_CAUSAL) { int ke = m0 + BM; kend = ke < Kd ? ke : Kd; }
        if (flags & FLAG_HALFK) kend = Kd >> 1;
        const int nk = kend >> 5;
        constexpr int NLD = BM / 64 + BN / 64;   // GLDS ops per wave per stage
        auto stage = [&](int t, int buf) {
            const int k0 = t << 5;
#pragma unroll
            for (int rb = 0; rb < BM / 64; ++rb) {
                int rowblk = wave * (BM / 64) + rb;
                int ml = rowblk * 16 + (lane >> 2);
                int qs = (lane & 3) ^ ((ml >> 1) & 3);
                GLDS(A + (size_t)(m0 + ml) * Kd + k0 + qs * 8, &sA[buf][rowblk * 512]);
            }
            // B staging: BN/64 may be 0 when BN=64 and 4 waves each cover 16
            // rows; use per-wave share = BN*32*2B / (4 waves * 64 lanes * 16B)
#pragma unroll
            for (int rb = 0; rb < BN / 64; ++rb) {
                int rowblk = wave * (BN / 64) + rb;
                int nl = rowblk * 16 + (lane >> 2);
                int qs = (lane & 3) ^ ((nl >> 1) & 3);
                GLDS(Bb + (size_t)(n0 + nl) * Kd + k0 + qs * 8, &sB[buf][rowblk * 512]);
            }
            if constexpr (BN == 64) {
                // one GLDS per wave covers 16 rows; 4 waves cover all 64 rows
                int nl = wave * 16 + (lane >> 2);
                int qs = (lane & 3) ^ ((nl >> 1) & 3);
                GLDS(Bb + (size_t)(n0 + nl) * Kd + k0 + qs * 8, &sB[buf][wave * 512]);
            }
        };
        auto compute = [&](int buf) {
            const bf16_t* sAc = sA[buf];
            const bf16_t* sBc = sB[buf];
            bf16x8 af[TM], bv[TN];
#pragma unroll
            for (int i = 0; i < TM; ++i) {
                int row = wm + i * 16 + lrow;
                af[i] = *(const bf16x8*)(sAc + (row * 4 + (quad ^ ((row >> 1) & 3))) * 8);
            }
#pragma unroll
            for (int j = 0; j < TN; ++j) {
                int rown = wn + j * 16 + lrow;
                bv[j] = *(const bf16x8*)(sBc + (rown * 4 + (quad ^ ((rown >> 1) & 3))) * 8);
            }
#pragma unroll
            for (int i = 0; i < TM; ++i)
#pragma unroll
                for (int j = 0; j < TN; ++j)
                    acc[i][j] = __builtin_amdgcn_mfma_f32_16x16x32_bf16(af[i], bv[j], acc[i][j], 0, 0, 0);
        };
        constexpr int NLDE = NLD + (BN == 64 ? 1 : 0);   // effective GLDS/wave
        if constexpr (NBUF == 2) {
            stage(0, 0);
            int cur = 0;
            for (int t = 0; t < nk; ++t) {
                if (t + 1 < nk) {
                    stage(t + 1, cur ^ 1);
                    asm volatile("s_waitcnt vmcnt(%0)" :: "n"(NLDE) : "memory");
                } else {
                    asm volatile("s_waitcnt vmcnt(0)" ::: "memory");
                }
                __builtin_amdgcn_s_barrier();
                compute(cur);
                asm volatile("s_waitcnt lgkmcnt(0)" ::: "memory");
                __builtin_amdgcn_s_barrier();
                cur ^= 1;
            }
        } else {
            // NBUF=3: triple buffer (explicit rotation), 2 stages in flight
            stage(0, 0);
            if (nk > 1) stage(1, 1);
            int b0 = 0;
            for (int t = 0; t < nk; ++t) {
                const int nxt = t + 2;
                if (nxt < nk) {
                    int bn = b0 + 2; if (bn >= 3) bn -= 3;
                    stage(nxt, bn);
                }
                const int last = (nxt < nk) ? nxt : nk - 1;
                const int ahead = last - t;
                if (ahead >= 2)      asm volatile("s_waitcnt vmcnt(%0)" :: "n"(2 * NLDE) : "memory");
                else if (ahead == 1) asm volatile("s_waitcnt vmcnt(%0)" :: "n"(1 * NLDE) : "memory");
                else                 asm volatile("s_waitcnt vmcnt(0)" ::: "memory");
                __builtin_amdgcn_s_barrier();
                compute(b0);
                asm volatile("s_waitcnt lgkmcnt(0)" ::: "memory");
                __builtin_amdgcn_s_barrier();
                b0 = (b0 == 2) ? 0 : b0 + 1;
            }
        }
    }

    // --- epilogue: C/D layout col=lane&15, row=quad*4+reg ---
    const size_t zo = (size_t)z * strC;
#pragma unroll
    for (int i = 0; i < TM; ++i) {
#pragma unroll
        for (int reg = 0; reg < 4; ++reg) {
            int m = m0 + wm + i * 16 + quad * 4 + reg;
            float rs = (flags & FLAG_INV) ? rsqrtf((float)(m + 1) * (float)K_) : 1.0f;
#pragma unroll
            for (int j = 0; j < TN; ++j) {
                int n = n0 + wn + j * 16 + lrow;
                float vv = acc[i][j][reg];
                if (bias) vv += bias[n];
                vv *= rs;
                if (flags & FLAG_TANH) vv = tanhf(vv);
                else if (flags & FLAG_GELU) vv = 0.5f * vv * (1.0f + erff(vv * 0.7071067811865476f));
                else if (flags & FLAG_TANHLO) { if (n < D_) vv = tanhf(vv); }
                if ((flags & FLAG_TRI) && n > m) vv = 0.f;
                size_t idx = zo + (size_t)m * N + n;
                if (res1) vv += res1[idx];
                if (res2) vv += res2[idx];
                if (Cf) Cf[idx] = vv;
                if (Cb) Cb[idx] = (bf16_t)vv;
            }
        }
    }
}

// ---------------------------------------------------------------------------
// Phase kernel: 4 rows per block (256 threads). Writes bf16 [cos|sin] into
// csb [row][64]. t1 rows strided 2*D (fused t1|v buffer).
// ---------------------------------------------------------------------------
__global__ __launch_bounds__(256) void phase_kernel(const float* __restrict__ t1,
                             const float* __restrict__ w2,
                             const float* __restrict__ b2,
                             const float* __restrict__ ps,
                             const float* __restrict__ cs,
                             int layer,
                             bf16_t* __restrict__ csb) {
    int tid = threadIdx.x;
    int rl = tid >> 6;                   // 0..3: row within block
    int k = tid & 31, hh = (tid >> 5) & 1;
    int row = blockIdx.x * 4 + rl;
    int l = row & (L_ - 1);
    const float* tr = t1 + (size_t)row * (2 * D_);
    float acc = 0.f;
    for (int d = hh * 256; d < hh * 256 + 256; ++d)
        acc = fmaf(tr[d], w2[d * K_ + k], acc);
    __shared__ float red[256];
    red[tid] = acc;
    __syncthreads();
    if (hh == 0) {
        float zz = red[rl * 64 + k] + red[rl * 64 + 32 + k] + b2[k];
        float cp = tanhf(zz) * 3.14159265358979323846f;
        float freq = expf(-(float)k * (9.210340371976184f / (float)K_));
        float tp = ps[layer] * (float)l * freq + cs[layer] * cp;
        csb[(size_t)row * 64 + k]      = (bf16_t)cosf(tp);
        csb[(size_t)row * 64 + 32 + k] = (bf16_t)sinf(tp);
    }
}

// ---------------------------------------------------------------------------
extern "C" void kernel_launch(void* const* d_in, const int* in_sizes, int n_in,
                              void* d_out, int out_size, void* d_ws, size_t ws_size,
                              hipStream_t stream) {
    const int*   tokens        = (const int*)d_in[0];
    const float* embed         = (const float*)d_in[1];
    const float* ln1_g         = (const float*)d_in[2];
    const float* ln1_b         = (const float*)d_in[3];
    const float* cp_w1         = (const float*)d_in[4];
    const float* cp_b1         = (const float*)d_in[5];
    const float* cp_w2         = (const float*)d_in[6];
    const float* cp_b2         = (const float*)d_in[7];
    const float* pos_scale     = (const float*)d_in[8];
    const float* content_scale = (const float*)d_in[9];
    const float* val_w         = (const float*)d_in[10];
    const float* val_b         = (const float*)d_in[11];
    const float* oln_g         = (const float*)d_in[12];
    const float* oln_b         = (const float*)d_in[13];
    const float* out_w         = (const float*)d_in[14];
    const float* out_b         = (const float*)d_in[15];
    const float* ln2_g         = (const float*)d_in[16];
    const float* ln2_b         = (const float*)d_in[17];
    const float* ffn_w1        = (const float*)d_in[18];
    const float* ffn_b1        = (const float*)d_in[19];
    const float* ffn_w2        = (const float*)d_in[20];
    const float* ffn_b2        = (const float*)d_in[21];
    const float* no_g          = (const float*)d_in[22];
    const float* no_b          = (const float*)d_in[23];
    const float* head_b        = (const float*)d_in[24];
    float* out = (float*)d_out;

    // Scratch in d_out (dead before head GEMM writes). hn_bf + emb_bf in d_ws.
    float* h   = out;                        // MR*D fp32
    float* x   = h  + (size_t)MR_ * D_;      // MR*D fp32
    float* t1v = x  + (size_t)MR_ * D_;      // MR*2D fp32 (t1 | v fused)
    float* r   = t1v + (size_t)MR_ * 2 * D_; // MR*D fp32
    bf16_t* x_bf  = (bf16_t*)(r + (size_t)MR_ * D_);
    bf16_t* r_bf  = x_bf  + (size_t)MR_ * D_;
    bf16_t* y_bf  = r_bf  + (size_t)MR_ * D_;
    bf16_t* ff_bf = y_bf  + (size_t)MR_ * D_;          // MR*FF
    bf16_t* sc_bf = ff_bf + (size_t)MR_ * FF_;         // B*L*L
    bf16_t* vT_bf = sc_bf + (size_t)B_ * L_ * L_;      // B*D*L
    bf16_t* csb   = vT_bf + (size_t)B_ * D_ * L_;      // MR*64 (cos|sin bf16)
    bf16_t* wvT   = csb   + (size_t)MR_ * 64;          // NL*2*D*D (w1T|vwT per layer)
    bf16_t* owT   = wvT   + (size_t)NL_ * 2 * D_ * D_;
    bf16_t* f1T   = owT   + (size_t)NL_ * D_ * D_;     // NL*FF*D
    bf16_t* f2T   = f1T   + (size_t)NL_ * FF_ * D_;    // NL*D*FF
    float*  b1v   = (float*)(f2T + (size_t)NL_ * D_ * FF_); // NL*2D fp32
    float*  pK    = b1v + (size_t)NL_ * 2 * D_;        // 2*MR*D fp32 split-K partials
    bf16_t* hn_bf = (bf16_t*)d_ws;                     // MR*D (2 MB)
    bf16_t* emb_bf = hn_bf + (size_t)MR_ * D_;         // V*D bf16 (32.8 MB)
    const bool big_ws =
        ws_size >= ((size_t)MR_ * D_ + (size_t)V_ * D_) * sizeof(bf16_t);

    gather_kernel<<<MR_, 128, 0, stream>>>(tokens, embed, h);

    // Pre-transpose + convert all weights to bf16 [N][K]
    // Fused t1|v weight: layer i rows [0,D) = cp_w1^T, rows [D,2D) = val_w^T
    tconv_kernel<<<dim3(16, 16, NL_), 256, 0, stream>>>(cp_w1, wvT, D_, D_, (size_t)D_ * D_, (size_t)2 * D_ * D_);
    tconv_kernel<<<dim3(16, 16, NL_), 256, 0, stream>>>(val_w, wvT + (size_t)D_ * D_, D_, D_, (size_t)D_ * D_, (size_t)2 * D_ * D_);
    bconcat_kernel<<<NL_, 512, 0, stream>>>(cp_b1, val_b, b1v);
    tconv_kernel<<<dim3(16, 16, NL_), 256, 0, stream>>>(out_w, owT, D_, D_, (size_t)D_ * D_, (size_t)D_ * D_);
    tconv_kernel<<<dim3(64, 16, NL_), 256, 0, stream>>>(ffn_w1, f1T, D_, FF_, (size_t)D_ * FF_, (size_t)D_ * FF_);
    tconv_kernel<<<dim3(16, 64, NL_), 256, 0, stream>>>(ffn_w2, f2T, FF_, D_, (size_t)FF_ * D_, (size_t)FF_ * D_);
    // embed is already [N=V][K=D]: straight convert to bf16 for the head GEMM
    if (big_ws)
        cvt_kernel<<<(V_ * D_) / 2048, 256, 0, stream>>>(embed, emb_bf);

    for (int i = 0; i < NL_; ++i) {
        // x = LN(h): explicit only for layer 0 (fused into prev sumk_ln after)
        if (i == 0)
            ln_kernel<<<MR_, 256, 0, stream>>>(h, ln1_g, ln1_b, x, x_bf);
        // t1v = [tanh(x @ cp_w1 + cp_b1) | x @ val_w + val_b]  (fused, N=1024)
        mgemm<64, 64, 3, 64, false><<<dim3(16, 32, 1), 256, 0, stream>>>(
            x_bf, wvT + (size_t)i * 2 * D_ * D_, b1v + (size_t)i * 2 * D_,
            nullptr, nullptr, t1v, nullptr, MR_, 2 * D_, D_, FLAG_TANHLO, 0, 0, 0, 1);
        // csb = bf16 [cos|sin] phases (reads t1 = cols [0,D) of t1v)
        phase_kernel<<<MR_ / 4, 256, 0, stream>>>(
            t1v, cp_w2 + (size_t)i * D_ * K_, cp_b2 + i * K_,
            pos_scale, content_scale, i, csb);
        // vT (bf16, [b][D][L]) from cols [D,2D) of t1v — coalesced LDS transpose
        tconv_kernel<<<dim3(16, 32, B_), 256, 0, stream>>>(
            t1v + D_, vT_bf, L_, 2 * D_, (size_t)L_ * 2 * D_, (size_t)D_ * L_);
        // scores = tri(CS @ CS^T)  (K=64 GEMM; lower-triangle blocks only)
        mgemm<64, 64, 3, 64, false><<<dim3(L_ / 64, L_ / 64, B_), 256, 0, stream>>>(
            csb, csb, nullptr, nullptr, nullptr, nullptr, sc_bf,
            L_, L_, 64, FLAG_TRI,
            (long long)L_ * 64, (long long)L_ * 64, (long long)L_ * L_, 0);
        // r = (A @ v) * inv_norm  (batched over z; causal K-loop)
        mgemm<64, 64, 3, 64, false><<<dim3(8, 16, B_), 256, 0, stream>>>(
            sc_bf, vT_bf, nullptr, nullptr, nullptr, r, nullptr,
            L_, D_, L_, FLAG_INV | FLAG_CAUSAL,
            (long long)L_ * L_, (long long)D_ * L_, (long long)L_ * D_, 1);
        // r_bf = LN(r)
        ln_kernel<<<MR_, 256, 0, stream>>>(r, oln_g + i * D_, oln_b + i * D_, nullptr, r_bf);
        // h = h + x + (r_bf @ out_w + out_b)
        mgemm<64, 64, 3, 64, false><<<dim3(8, 32, 1), 256, 0, stream>>>(
            r_bf, owT + (size_t)i * D_ * D_, out_b + i * D_,
            h, x, h, nullptr, MR_, D_, D_, 0, 0, 0, 0, 1);
        // y_bf = LN(h)
        ln_kernel<<<MR_, 256, 0, stream>>>(h, ln2_g + i * D_, ln2_b + i * D_, nullptr, y_bf);
        // ff_bf = gelu(y @ ffn_w1 + b1)  (bf16 only; 64² -> 1024 blocks, 3/CU)
        mgemm<64, 64, 3, 64, false><<<dim3(32, 32, 1), 256, 0, stream>>>(
            y_bf, f1T + (size_t)i * FF_ * D_, ffn_b1 + i * FF_,
            nullptr, nullptr, nullptr, ff_bf, MR_, FF_, D_, FLAG_GELU, 0, 0, 0, 1);
        // ffn2 split-K=2: pK[z] = ff[:, z*FF/2:(z+1)*FF/2] @ f2T[z-chunk]
        mgemm<64, 64, 3, 64, false><<<dim3(8, 32, 2), 256, 0, stream>>>(
            ff_bf, f2T + (size_t)i * D_ * FF_, nullptr,
            nullptr, nullptr, pK, nullptr, MR_, D_, FF_, FLAG_HALFK,
            (long long)(FF_ / 2), (long long)(FF_ / 2), (long long)MR_ * D_, 1);
        // h += pK0 + pK1 + ffn_b2, fused with next LN:
        //   layers 0..NL-2 -> next layer's ln1 (x, x_bf); last -> final LN (hn_bf)
        if (i < NL_ - 1) {
            sumk_ln_kernel<<<MR_, 256, 0, stream>>>(
                pK, pK + (size_t)MR_ * D_, ffn_b2 + i * D_, h,
                ln1_g + (i + 1) * D_, ln1_b + (i + 1) * D_, x, x_bf);
        } else {
            sumk_ln_kernel<<<MR_, 256, 0, stream>>>(
                pK, pK + (size_t)MR_ * D_, ffn_b2 + i * D_, h,
                no_g, no_b, nullptr, hn_bf);
        }
    }

    // out = hn @ embed^T + head_b   (BN=64 -> 36 KB LDS -> 4 blocks/CU)
    if (big_ws) {
        mgemm<128, 64, 3, 32, false><<<dim3(V_ / 64, MR_ / 128, 1), 256, 0, stream>>>(
            hn_bf, emb_bf, head_b, nullptr, nullptr, out, nullptr,
            MR_, V_, D_, 0, 0, 0, 0, 1);
    } else {
        mgemm<128, 128, 1, 32, true><<<dim3(V_ / 128, MR_ / 128, 1), 256, 0, stream>>>(
            hn_bf, embed, head_b, nullptr, nullptr, out, nullptr,
            MR_, V_, D_, 0, 0, 0, 0, 1);
    }
}

// Round 12
// 1312.457 us; speedup vs baseline: 1.0969x; 1.0039x over previous
//
#include <hip/hip_runtime.h>
#include <hip/hip_bf16.h>
#include <math.h>

// Problem constants
#define V_  32000
#define D_  512
#define NL_ 4
#define K_  32
#define B_  2
#define L_  1024
#define FF_ 2048
#define MR_ (B_ * L_)   // 2048 total rows

typedef __bf16 bf16_t;
typedef __bf16 bf16x8 __attribute__((ext_vector_type(8)));
typedef float  f32x4  __attribute__((ext_vector_type(4)));

#define FLAG_TANH   1
#define FLAG_GELU   2
#define FLAG_INV    8
#define FLAG_CAUSAL 16
#define FLAG_TANHLO 32   // tanh applied only to columns n < D_ (fused t1|v GEMM)
#define FLAG_TRI    64   // triangular score GEMM: skip bx>by blocks, zero n>m
#define FLAG_HALFK  128  // split-K: this dispatch covers Kd/2 (z selects chunk)

// async 16B global->LDS (wave-uniform LDS base + lane*16)
#define GLDS(gsrc, ldst) \
  __builtin_amdgcn_global_load_lds( \
      (const __attribute__((address_space(1))) unsigned int*)(const void*)(gsrc), \
      (__attribute__((address_space(3))) unsigned int*)(void*)(ldst), 16, 0, 0)

// ---------------------------------------------------------------------------
// Embedding gather
// ---------------------------------------------------------------------------
__global__ void gather_kernel(const int* __restrict__ tokens,
                              const float* __restrict__ embed,
                              float* __restrict__ h) {
    int row = blockIdx.x;
    int t = tokens[row];
    const float4* src = (const float4*)(embed + (size_t)t * D_);
    float4* dst = (float4*)(h + (size_t)row * D_);
    dst[threadIdx.x] = src[threadIdx.x];
}

// ---------------------------------------------------------------------------
// fp32 -> bf16 bulk convert (row-major, no transpose). count % 2048 == 0.
// ---------------------------------------------------------------------------
__global__ __launch_bounds__(256) void cvt_kernel(const float* __restrict__ in,
                                                  bf16_t* __restrict__ out) {
    size_t i = ((size_t)blockIdx.x * 256 + threadIdx.x) * 8;
    float4 f0 = ((const float4*)(in + i))[0];
    float4 f1 = ((const float4*)(in + i))[1];
    bf16x8 ov;
    ov[0] = (bf16_t)f0.x; ov[1] = (bf16_t)f0.y;
    ov[2] = (bf16_t)f0.z; ov[3] = (bf16_t)f0.w;
    ov[4] = (bf16_t)f1.x; ov[5] = (bf16_t)f1.y;
    ov[6] = (bf16_t)f1.z; ov[7] = (bf16_t)f1.w;
    *(bf16x8*)(out + i) = ov;
}

// ---------------------------------------------------------------------------
// Bias concat: o[i][0:D) = a[i], o[i][D:2D) = b[i]
// ---------------------------------------------------------------------------
__global__ void bconcat_kernel(const float* __restrict__ a,
                               const float* __restrict__ b,
                               float* __restrict__ o) {
    int i = blockIdx.x, t = threadIdx.x;   // block 512
    o[(size_t)i * 2 * D_ + t]       = a[(size_t)i * D_ + t];
    o[(size_t)i * 2 * D_ + D_ + t]  = b[(size_t)i * D_ + t];
}

// ---------------------------------------------------------------------------
// LayerNorm over D=512; optional fp32 and bf16 outputs.
// ---------------------------------------------------------------------------
__global__ __launch_bounds__(256) void ln_kernel(const float* __restrict__ in,
                                                 const float* __restrict__ g,
                                                 const float* __restrict__ b,
                                                 float* __restrict__ outf,
                                                 bf16_t* __restrict__ outb) {
    int row = blockIdx.x, tid = threadIdx.x;
    const float* rp = in + (size_t)row * D_;
    float v0 = rp[tid], v1 = rp[tid + 256];
    float s = v0 + v1, q = v0 * v0 + v1 * v1;
#pragma unroll
    for (int o = 32; o > 0; o >>= 1) {
        s += __shfl_down(s, o, 64);
        q += __shfl_down(q, o, 64);
    }
    __shared__ float ss[4], sq[4];
    if ((tid & 63) == 0) { ss[tid >> 6] = s; sq[tid >> 6] = q; }
    __syncthreads();
    float ts = ss[0] + ss[1] + ss[2] + ss[3];
    float tq = sq[0] + sq[1] + sq[2] + sq[3];
    float mean = ts * (1.0f / D_);
    float var = tq * (1.0f / D_) - mean * mean;
    float rstd = rsqrtf(var + 1e-5f);
    float o0 = (v0 - mean) * rstd * g[tid] + b[tid];
    float o1 = (v1 - mean) * rstd * g[tid + 256] + b[tid + 256];
    if (outf) {
        outf[(size_t)row * D_ + tid]       = o0;
        outf[(size_t)row * D_ + tid + 256] = o1;
    }
    if (outb) {
        outb[(size_t)row * D_ + tid]       = (bf16_t)o0;
        outb[(size_t)row * D_ + tid + 256] = (bf16_t)o1;
    }
}

// ---------------------------------------------------------------------------
// Fused split-K sum + LayerNorm (coalesced; numerics = sumk then ln).
// ---------------------------------------------------------------------------
__global__ __launch_bounds__(256) void sumk_ln_kernel(
    const float* __restrict__ p0, const float* __restrict__ p1,
    const float* __restrict__ bias, float* __restrict__ h,
    const float* __restrict__ g, const float* __restrict__ b,
    float* __restrict__ outf, bf16_t* __restrict__ outb) {
    int row = blockIdx.x, tid = threadIdx.x;
    size_t o = (size_t)row * D_;
    float v0 = h[o + tid]       + p0[o + tid]       + p1[o + tid]       + bias[tid];
    float v1 = h[o + tid + 256] + p0[o + tid + 256] + p1[o + tid + 256] + bias[tid + 256];
    h[o + tid]       = v0;
    h[o + tid + 256] = v1;
    float s = v0 + v1, q = v0 * v0 + v1 * v1;
#pragma unroll
    for (int of = 32; of > 0; of >>= 1) {
        s += __shfl_down(s, of, 64);
        q += __shfl_down(q, of, 64);
    }
    __shared__ float ss[4], sq[4];
    if ((tid & 63) == 0) { ss[tid >> 6] = s; sq[tid >> 6] = q; }
    __syncthreads();
    float ts = ss[0] + ss[1] + ss[2] + ss[3];
    float tq = sq[0] + sq[1] + sq[2] + sq[3];
    float mean = ts * (1.0f / D_);
    float var = tq * (1.0f / D_) - mean * mean;
    float rstd = rsqrtf(var + 1e-5f);
    float o0 = (v0 - mean) * rstd * g[tid] + b[tid];
    float o1 = (v1 - mean) * rstd * g[tid + 256] + b[tid + 256];
    if (outf) {
        outf[o + tid]       = o0;
        outf[o + tid + 256] = o1;
    }
    outb[o + tid]       = (bf16_t)o0;
    outb[o + tid + 256] = (bf16_t)o1;
}

// ---------------------------------------------------------------------------
// Transpose + fp32->bf16 convert: in fp32 [R][C-strided] -> out bf16 [.][R]
// grid (cols/32, R/32, Z), block 256
// ---------------------------------------------------------------------------
__global__ __launch_bounds__(256) void tconv_kernel(const float* __restrict__ in,
                                                    bf16_t* __restrict__ out,
                                                    int R, int C,
                                                    size_t inz, size_t outz) {
    __shared__ float t[32][33];
    const float* ip = in + (size_t)blockIdx.z * inz;
    bf16_t* op = out + (size_t)blockIdx.z * outz;
    int r0 = blockIdx.y * 32, c0 = blockIdx.x * 32;
    int tx = threadIdx.x & 31, ty = threadIdx.x >> 5;  // ty in [0,8)
#pragma unroll
    for (int rr = 0; rr < 4; ++rr)
        t[ty + rr * 8][tx] = ip[(size_t)(r0 + ty + rr * 8) * C + c0 + tx];
    __syncthreads();
#pragma unroll
    for (int rr = 0; rr < 4; ++rr)
        op[(size_t)(c0 + ty + rr * 8) * R + r0 + tx] = (bf16_t)t[tx][ty + rr * 8];
}

// ---------------------------------------------------------------------------
// Fused phasor attention: r[b][m][d] = (sum_{j<=m} S[m][j]*v[j][d]) * invn(m)
// with S[m][j] = sum_k CS[m][k]*CS[j][k]  (bf16 MFMA, fp32 acc, bf16 re-round
// before PV — numerically identical to the old score-GEMM + r-GEMM pair).
// grid (D/64, L/64, B), block 256 (4 waves, 2x2 over the 64x64 out tile).
// ---------------------------------------------------------------------------
__global__ __launch_bounds__(256) void phattn_kernel(
    const bf16_t* __restrict__ csb,   // [b][l][64]
    const bf16_t* __restrict__ vT,    // [b][d][l]
    float* __restrict__ r) {          // [b][l][d]
    __shared__ bf16_t sQ[64 * 64];
    __shared__ bf16_t sK[64 * 64];
    __shared__ bf16_t sV[64 * 64];
    __shared__ bf16_t sS[64][72];     // padded: stride 144B
    const int tid = threadIdx.x;
    const int wave = tid >> 6, lane = tid & 63;
    const int lrow = lane & 15, quad = lane >> 4;
    const int wm = (wave >> 1) * 32, wn = (wave & 1) * 32;
    const int b = blockIdx.z;
    const int m0 = blockIdx.y * 64, d0 = blockIdx.x * 64;
    const bf16_t* cs = csb + (size_t)b * L_ * 64;
    const bf16_t* vz = vT + (size_t)b * D_ * L_;
#pragma unroll
    for (int p = 0; p < 2; ++p) {
        int s = p * 256 + tid;            // 512 chunks of 8 bf16
        int row = s >> 3, c8 = s & 7;
        *(bf16x8*)(sQ + row * 64 + c8 * 8) =
            *(const bf16x8*)(cs + (size_t)(m0 + row) * 64 + c8 * 8);
    }
    f32x4 racc[2][2] = {};
    const int njt = (m0 >> 6) + 1;        // causal: j-tiles 0..mt
    for (int jt = 0; jt < njt; ++jt) {
        const int j0 = jt * 64;
        __syncthreads();                  // prev iter's sK/sV/sS reads done
#pragma unroll
        for (int p = 0; p < 2; ++p) {
            int s = p * 256 + tid;
            int row = s >> 3, c8 = s & 7;
            *(bf16x8*)(sK + row * 64 + c8 * 8) =
                *(const bf16x8*)(cs + (size_t)(j0 + row) * 64 + c8 * 8);
            *(bf16x8*)(sV + row * 64 + c8 * 8) =
                *(const bf16x8*)(vz + (size_t)(d0 + row) * L_ + j0 + c8 * 8);
        }
        __syncthreads();
        // ---- S = Q @ K^T (64x64, K=64) ----
        f32x4 sacc[2][2] = {};
#pragma unroll
        for (int ks = 0; ks < 2; ++ks) {
            bf16x8 qa[2], kb[2];
#pragma unroll
            for (int i = 0; i < 2; ++i)
                qa[i] = *(const bf16x8*)(sQ + (wm + i * 16 + lrow) * 64 + ks * 32 + quad * 8);
#pragma unroll
            for (int j = 0; j < 2; ++j)
                kb[j] = *(const bf16x8*)(sK + (wn + j * 16 + lrow) * 64 + ks * 32 + quad * 8);
#pragma unroll
            for (int i = 0; i < 2; ++i)
#pragma unroll
                for (int j = 0; j < 2; ++j)
                    sacc[i][j] = __builtin_amdgcn_mfma_f32_16x16x32_bf16(qa[i], kb[j], sacc[i][j], 0, 0, 0);
        }
        // ---- tri-mask + bf16 -> LDS (C/D layout: col=lane&15, row=quad*4+reg)
#pragma unroll
        for (int i = 0; i < 2; ++i)
#pragma unroll
            for (int reg = 0; reg < 4; ++reg)
#pragma unroll
                for (int j = 0; j < 2; ++j) {
                    int mm = wm + i * 16 + quad * 4 + reg;   // local S row
                    int jj = wn + j * 16 + lrow;             // local S col
                    float vv = sacc[i][j][reg];
                    if (j0 + jj > m0 + mm) vv = 0.f;
                    sS[mm][jj] = (bf16_t)vv;
                }
        __syncthreads();
        // ---- racc += S @ V^T (out m x d; k = j) ----
#pragma unroll
        for (int ks = 0; ks < 2; ++ks) {
            bf16x8 pa[2], vb[2];
#pragma unroll
            for (int i = 0; i < 2; ++i)
                pa[i] = *(const bf16x8*)(&sS[wm + i * 16 + lrow][ks * 32 + quad * 8]);
#pragma unroll
            for (int j = 0; j < 2; ++j)
                vb[j] = *(const bf16x8*)(sV + (wn + j * 16 + lrow) * 64 + ks * 32 + quad * 8);
#pragma unroll
            for (int i = 0; i < 2; ++i)
#pragma unroll
                for (int j = 0; j < 2; ++j)
                    racc[i][j] = __builtin_amdgcn_mfma_f32_16x16x32_bf16(pa[i], vb[j], racc[i][j], 0, 0, 0);
        }
    }
    // ---- epilogue: r = racc * rsqrt((m+1)*K) ----
#pragma unroll
    for (int i = 0; i < 2; ++i)
#pragma unroll
        for (int reg = 0; reg < 4; ++reg) {
            int m = m0 + wm + i * 16 + quad * 4 + reg;
            float rs = rsqrtf((float)(m + 1) * (float)K_);
#pragma unroll
            for (int j = 0; j < 2; ++j) {
                int d = d0 + wn + j * 16 + lrow;
                r[(size_t)b * L_ * D_ + (size_t)m * D_ + d] = racc[i][j][reg] * rs;
            }
        }
}

// ---------------------------------------------------------------------------
// MFMA bf16 GEMM: C[M,N] = epilogue(A[M,K] @ B^T[N,K])
//   BK=32 path: head (128x64, NBUF=3, 36 KB -> 4 blocks/CU; shape-bound
//     ~210 us per m102 curve). BK=64 path: layer GEMMs (XOR-swizzled LDS).
// flags: 1 tanh, 2 gelu, 8 inv, 16 causal, 32 tanh-lo, 64 tri, 128 half-K.
// swz: bijective XCD-chunked block remap, m-fast within each n-panel chunk.
// ---------------------------------------------------------------------------
template<int BM, int BN, int NBUF, int BK, bool BF32>
__global__ __launch_bounds__(256) void mgemm(
    const bf16_t* __restrict__ A, const void* __restrict__ Bp,
    const float* __restrict__ bias, const float* __restrict__ res1,
    const float* __restrict__ res2, float* __restrict__ Cf,
    bf16_t* __restrict__ Cb, int M, int N, int Kd, int flags,
    long long strA, long long strB, long long strC, int swz) {
    __shared__ bf16_t sA[NBUF][BM * BK];
    __shared__ bf16_t sB[NBUF][BN * BK];
    const int tid = threadIdx.x;
    const int wave = tid >> 6, lane = tid & 63;
    const int lrow = lane & 15, quad = lane >> 4;
    int bx = blockIdx.x, by = blockIdx.y;
    if (swz) {
        int gx = gridDim.x, gy = gridDim.y;
        int nwg = gx * gy;
        int lid = by * gx + bx;
        int q = nwg >> 3, r = nwg & 7;
        int xcd = lid & 7, slot = lid >> 3;
        int base = (xcd < r) ? xcd * (q + 1) : r * (q + 1) + (xcd - r) * q;
        int nid = base + slot;       // contiguous chunk per XCD
        bx = nid / gy;               // n varies slowly
        by = nid - bx * gy;          // m fast within an n-panel
    }
    if ((flags & FLAG_TRI) && bx > by) return;   // strictly-upper: never read
    const int m0 = by * BM, n0 = bx * BN;
    const int z = blockIdx.z;
    A += (size_t)z * strA;
    const bf16_t* Bb = (const bf16_t*)Bp + (BF32 ? 0 : (size_t)z * strB);
    const float*  Bf = (const float*)Bp  + (BF32 ? (size_t)z * strB : 0);
    constexpr int TM = BM / 32, TN = BN / 32;  // 16x16 tiles per wave dim
    const int wm = (wave >> 1) * (BM / 2), wn = (wave & 1) * (BN / 2);
    f32x4 acc[TM][TN] = {};

    if constexpr (BF32) {
        // -------- fallback: single-buffered, fp32 B convert-staging --------
        for (int k0 = 0; k0 < Kd; k0 += 32) {
#pragma unroll
            for (int rb = 0; rb < BM / 64; ++rb) {
                int rowblk = wave * (BM / 64) + rb;
                int ml = rowblk * 16 + (lane >> 2);
                int qs = (lane & 3) ^ ((ml >> 1) & 3);
                GLDS(A + (size_t)(m0 + ml) * Kd + k0 + qs * 8, &sA[0][rowblk * 512]);
            }
#pragma unroll
            for (int rb = 0; rb < (BN * 4) / 256; ++rb) {
                int s = rb * 256 + tid;
                int nl = s >> 2, ql = s & 3;
                int qs = ql ^ ((nl >> 1) & 3);
                const float* src = Bf + (size_t)(n0 + nl) * Kd + k0 + qs * 8;
                float4 f0 = ((const float4*)src)[0];
                float4 f1 = ((const float4*)src)[1];
                bf16x8 ov;
                ov[0] = (bf16_t)f0.x; ov[1] = (bf16_t)f0.y;
                ov[2] = (bf16_t)f0.z; ov[3] = (bf16_t)f0.w;
                ov[4] = (bf16_t)f1.x; ov[5] = (bf16_t)f1.y;
                ov[6] = (bf16_t)f1.z; ov[7] = (bf16_t)f1.w;
                *(bf16x8*)(&sB[0][s * 8]) = ov;
            }
            __syncthreads();
            bf16x8 af[TM], bv[TN];
#pragma unroll
            for (int i = 0; i < TM; ++i) {
                int row = wm + i * 16 + lrow;
                af[i] = *(const bf16x8*)(&sA[0][(row * 4 + (quad ^ ((row >> 1) & 3))) * 8]);
            }
#pragma unroll
            for (int j = 0; j < TN; ++j) {
                int rown = wn + j * 16 + lrow;
                bv[j] = *(const bf16x8*)(&sB[0][(rown * 4 + (quad ^ ((rown >> 1) & 3))) * 8]);
            }
#pragma unroll
            for (int i = 0; i < TM; ++i)
#pragma unroll
                for (int j = 0; j < TN; ++j)
                    acc[i][j] = __builtin_amdgcn_mfma_f32_16x16x32_bf16(af[i], bv[j], acc[i][j], 0, 0, 0);
            __syncthreads();
        }
    } else if constexpr (BK == 64) {
        // -------- BK=64: 8-row GLDS groups, XOR-swizzled chunks --------
        int kend = Kd;
        if (flags & FLAG_CAUSAL) { int ke = m0 + BM; kend = ke < Kd ? ke : Kd; }
        if (flags & FLAG_HALFK) kend = Kd >> 1;
        const int nk = kend >> 6;
        constexpr int NLD = BM / 32 + BN / 32;   // GLDS per wave per stage
        auto stage = [&](int t, int buf) {
            const int k0 = t << 6;
#pragma unroll
            for (int rb = 0; rb < BM / 32; ++rb) {
                int r0 = (wave * (BM / 32) + rb) * 8;
                int row = r0 + (lane >> 3);
                int cs_ = (lane & 7) ^ (row & 7);
                GLDS(A + (size_t)(m0 + row) * Kd + k0 + cs_ * 8, &sA[buf][r0 * 64]);
            }
#pragma unroll
            for (int rb = 0; rb < BN / 32; ++rb) {
                int r0 = (wave * (BN / 32) + rb) * 8;
                int row = r0 + (lane >> 3);
                int cs_ = (lane & 7) ^ (row & 7);
                GLDS(Bb + (size_t)(n0 + row) * Kd + k0 + cs_ * 8, &sB[buf][r0 * 64]);
            }
        };
        auto compute = [&](int buf) {
            const bf16_t* sAc = sA[buf];
            const bf16_t* sBc = sB[buf];
            bf16x8 a0[TM], a1[TM], b0[TN], b1[TN];
#pragma unroll
            for (int i = 0; i < TM; ++i) {
                int row = wm + i * 16 + lrow;
                a0[i] = *(const bf16x8*)(sAc + row * 64 + ((quad       ^ (row & 7)) * 8));
                a1[i] = *(const bf16x8*)(sAc + row * 64 + (((4 | quad) ^ (row & 7)) * 8));
            }
#pragma unroll
            for (int j = 0; j < TN; ++j) {
                int rown = wn + j * 16 + lrow;
                b0[j] = *(const bf16x8*)(sBc + rown * 64 + ((quad       ^ (rown & 7)) * 8));
                b1[j] = *(const bf16x8*)(sBc + rown * 64 + (((4 | quad) ^ (rown & 7)) * 8));
            }
#pragma unroll
            for (int i = 0; i < TM; ++i)
#pragma unroll
                for (int j = 0; j < TN; ++j)
                    acc[i][j] = __builtin_amdgcn_mfma_f32_16x16x32_bf16(a0[i], b0[j], acc[i][j], 0, 0, 0);
#pragma unroll
            for (int i = 0; i < TM; ++i)
#pragma unroll
                for (int j = 0; j < TN; ++j)
                    acc[i][j] = __builtin_amdgcn_mfma_f32_16x16x32_bf16(a1[i], b1[j], acc[i][j], 0, 0, 0);
        };
        for (int t = 0; t < NBUF - 1 && t < nk; ++t) stage(t, t);
        int bcur = 0;
        for (int t = 0; t < nk; ++t) {
            const int nxt = t + NBUF - 1;
            if (nxt < nk) {
                int bn = bcur + NBUF - 1; if (bn >= NBUF) bn -= NBUF;
                stage(nxt, bn);
            }
            const int last = (nxt < nk) ? nxt : nk - 1;
            const int ahead = last - t;
            if (ahead >= 2)      asm volatile("s_waitcnt vmcnt(%0)" :: "n"(2 * NLD) : "memory");
            else if (ahead == 1) asm volatile("s_waitcnt vmcnt(%0)" :: "n"(1 * NLD) : "memory");
            else                 asm volatile("s_waitcnt vmcnt(0)" ::: "memory");
            __builtin_amdgcn_s_barrier();
            compute(bcur);
            asm volatile("s_waitcnt lgkmcnt(0)" ::: "memory");
            __builtin_amdgcn_s_barrier();
            bcur = (bcur + 1 == NBUF) ? 0 : bcur + 1;
        }
    } else {
        // -------- BK=32 (head) --------
        int kend = Kd;
        if (flags & FLAG_CAUSAL) { int ke = m0 + BM; kend = ke < Kd ? ke : Kd; }
        if (flags & FLAG_HALFK) kend = Kd >> 1;
        const int nk = kend >> 5;
        constexpr int NLD = BM / 64 + BN / 64;   // GLDS ops per wave per stage
        auto stage = [&](int t, int buf) {
            const int k0 = t << 5;
#pragma unroll
            for (int rb = 0; rb < BM / 64; ++rb) {
                int rowblk = wave * (BM / 64) + rb;
                int ml = rowblk * 16 + (lane >> 2);
                int qs = (lane & 3) ^ ((ml >> 1) & 3);
                GLDS(A + (size_t)(m0 + ml) * Kd + k0 + qs * 8, &sA[buf][rowblk * 512]);
            }
#pragma unroll
            for (int rb = 0; rb < BN / 64; ++rb) {
                int rowblk = wave * (BN / 64) + rb;
                int nl = rowblk * 16 + (lane >> 2);
                int qs = (lane & 3) ^ ((nl >> 1) & 3);
                GLDS(Bb + (size_t)(n0 + nl) * Kd + k0 + qs * 8, &sB[buf][rowblk * 512]);
            }
            if constexpr (BN == 64) {
                // one GLDS per wave covers 16 rows; 4 waves cover all 64 rows
                int nl = wave * 16 + (lane >> 2);
                int qs = (lane & 3) ^ ((nl >> 1) & 3);
                GLDS(Bb + (size_t)(n0 + nl) * Kd + k0 + qs * 8, &sB[buf][wave * 512]);
            }
        };
        auto compute = [&](int buf) {
            const bf16_t* sAc = sA[buf];
            const bf16_t* sBc = sB[buf];
            bf16x8 af[TM], bv[TN];
#pragma unroll
            for (int i = 0; i < TM; ++i) {
                int row = wm + i * 16 + lrow;
                af[i] = *(const bf16x8*)(sAc + (row * 4 + (quad ^ ((row >> 1) & 3))) * 8);
            }
#pragma unroll
            for (int j = 0; j < TN; ++j) {
                int rown = wn + j * 16 + lrow;
                bv[j] = *(const bf16x8*)(sBc + (rown * 4 + (quad ^ ((rown >> 1) & 3))) * 8);
            }
#pragma unroll
            for (int i = 0; i < TM; ++i)
#pragma unroll
                for (int j = 0; j < TN; ++j)
                    acc[i][j] = __builtin_amdgcn_mfma_f32_16x16x32_bf16(af[i], bv[j], acc[i][j], 0, 0, 0);
        };
        constexpr int NLDE = NLD + (BN == 64 ? 1 : 0);   // effective GLDS/wave
        if constexpr (NBUF == 2) {
            stage(0, 0);
            int cur = 0;
            for (int t = 0; t < nk; ++t) {
                if (t + 1 < nk) {
                    stage(t + 1, cur ^ 1);
                    asm volatile("s_waitcnt vmcnt(%0)" :: "n"(NLDE) : "memory");
                } else {
                    asm volatile("s_waitcnt vmcnt(0)" ::: "memory");
                }
                __builtin_amdgcn_s_barrier();
                compute(cur);
                asm volatile("s_waitcnt lgkmcnt(0)" ::: "memory");
                __builtin_amdgcn_s_barrier();
                cur ^= 1;
            }
        } else {
            // NBUF=3: triple buffer (explicit rotation), 2 stages in flight
            stage(0, 0);
            if (nk > 1) stage(1, 1);
            int b0 = 0;
            for (int t = 0; t < nk; ++t) {
                const int nxt = t + 2;
                if (nxt < nk) {
                    int bn = b0 + 2; if (bn >= 3) bn -= 3;
                    stage(nxt, bn);
                }
                const int last = (nxt < nk) ? nxt : nk - 1;
                const int ahead = last - t;
                if (ahead >= 2)      asm volatile("s_waitcnt vmcnt(%0)" :: "n"(2 * NLDE) : "memory");
                else if (ahead == 1) asm volatile("s_waitcnt vmcnt(%0)" :: "n"(1 * NLDE) : "memory");
                else                 asm volatile("s_waitcnt vmcnt(0)" ::: "memory");
                __builtin_amdgcn_s_barrier();
                compute(b0);
                asm volatile("s_waitcnt lgkmcnt(0)" ::: "memory");
                __builtin_amdgcn_s_barrier();
                b0 = (b0 == 2) ? 0 : b0 + 1;
            }
        }
    }

    // --- epilogue: C/D layout col=lane&15, row=quad*4+reg ---
    const size_t zo = (size_t)z * strC;
#pragma unroll
    for (int i = 0; i < TM; ++i) {
#pragma unroll
        for (int reg = 0; reg < 4; ++reg) {
            int m = m0 + wm + i * 16 + quad * 4 + reg;
            float rs = (flags & FLAG_INV) ? rsqrtf((float)(m + 1) * (float)K_) : 1.0f;
#pragma unroll
            for (int j = 0; j < TN; ++j) {
                int n = n0 + wn + j * 16 + lrow;
                float vv = acc[i][j][reg];
                if (bias) vv += bias[n];
                vv *= rs;
                if (flags & FLAG_TANH) vv = tanhf(vv);
                else if (flags & FLAG_GELU) vv = 0.5f * vv * (1.0f + erff(vv * 0.7071067811865476f));
                else if (flags & FLAG_TANHLO) { if (n < D_) vv = tanhf(vv); }
                if ((flags & FLAG_TRI) && n > m) vv = 0.f;
                size_t idx = zo + (size_t)m * N + n;
                if (res1) vv += res1[idx];
                if (res2) vv += res2[idx];
                if (Cf) Cf[idx] = vv;
                if (Cb) Cb[idx] = (bf16_t)vv;
            }
        }
    }
}

// ---------------------------------------------------------------------------
// Phase kernel: 4 rows per block (256 threads). Writes bf16 [cos|sin] into
// csb [row][64]. t1 rows strided 2*D (fused t1|v buffer).
// ---------------------------------------------------------------------------
__global__ __launch_bounds__(256) void phase_kernel(const float* __restrict__ t1,
                             const float* __restrict__ w2,
                             const float* __restrict__ b2,
                             const float* __restrict__ ps,
                             const float* __restrict__ cs,
                             int layer,
                             bf16_t* __restrict__ csb) {
    int tid = threadIdx.x;
    int rl = tid >> 6;                   // 0..3: row within block
    int k = tid & 31, hh = (tid >> 5) & 1;
    int row = blockIdx.x * 4 + rl;
    int l = row & (L_ - 1);
    const float* tr = t1 + (size_t)row * (2 * D_);
    float acc = 0.f;
    for (int d = hh * 256; d < hh * 256 + 256; ++d)
        acc = fmaf(tr[d], w2[d * K_ + k], acc);
    __shared__ float red[256];
    red[tid] = acc;
    __syncthreads();
    if (hh == 0) {
        float zz = red[rl * 64 + k] + red[rl * 64 + 32 + k] + b2[k];
        float cp = tanhf(zz) * 3.14159265358979323846f;
        float freq = expf(-(float)k * (9.210340371976184f / (float)K_));
        float tp = ps[layer] * (float)l * freq + cs[layer] * cp;
        csb[(size_t)row * 64 + k]      = (bf16_t)cosf(tp);
        csb[(size_t)row * 64 + 32 + k] = (bf16_t)sinf(tp);
    }
}

// ---------------------------------------------------------------------------
extern "C" void kernel_launch(void* const* d_in, const int* in_sizes, int n_in,
                              void* d_out, int out_size, void* d_ws, size_t ws_size,
                              hipStream_t stream) {
    const int*   tokens        = (const int*)d_in[0];
    const float* embed         = (const float*)d_in[1];
    const float* ln1_g         = (const float*)d_in[2];
    const float* ln1_b         = (const float*)d_in[3];
    const float* cp_w1         = (const float*)d_in[4];
    const float* cp_b1         = (const float*)d_in[5];
    const float* cp_w2         = (const float*)d_in[6];
    const float* cp_b2         = (const float*)d_in[7];
    const float* pos_scale     = (const float*)d_in[8];
    const float* content_scale = (const float*)d_in[9];
    const float* val_w         = (const float*)d_in[10];
    const float* val_b         = (const float*)d_in[11];
    const float* oln_g         = (const float*)d_in[12];
    const float* oln_b         = (const float*)d_in[13];
    const float* out_w         = (const float*)d_in[14];
    const float* out_b         = (const float*)d_in[15];
    const float* ln2_g         = (const float*)d_in[16];
    const float* ln2_b         = (const float*)d_in[17];
    const float* ffn_w1        = (const float*)d_in[18];
    const float* ffn_b1        = (const float*)d_in[19];
    const float* ffn_w2        = (const float*)d_in[20];
    const float* ffn_b2        = (const float*)d_in[21];
    const float* no_g          = (const float*)d_in[22];
    const float* no_b          = (const float*)d_in[23];
    const float* head_b        = (const float*)d_in[24];
    float* out = (float*)d_out;

    // Scratch in d_out (dead before head GEMM writes). hn_bf + emb_bf in d_ws.
    float* h   = out;                        // MR*D fp32
    float* x   = h  + (size_t)MR_ * D_;      // MR*D fp32
    float* t1v = x  + (size_t)MR_ * D_;      // MR*2D fp32 (t1 | v fused)
    float* r   = t1v + (size_t)MR_ * 2 * D_; // MR*D fp32
    bf16_t* x_bf  = (bf16_t*)(r + (size_t)MR_ * D_);
    bf16_t* r_bf  = x_bf  + (size_t)MR_ * D_;
    bf16_t* y_bf  = r_bf  + (size_t)MR_ * D_;
    bf16_t* ff_bf = y_bf  + (size_t)MR_ * D_;          // MR*FF
    bf16_t* sc_bf = ff_bf + (size_t)MR_ * FF_;         // B*L*L (unused now)
    bf16_t* vT_bf = sc_bf + (size_t)B_ * L_ * L_;      // B*D*L
    bf16_t* csb   = vT_bf + (size_t)B_ * D_ * L_;      // MR*64 (cos|sin bf16)
    bf16_t* wvT   = csb   + (size_t)MR_ * 64;          // NL*2*D*D (w1T|vwT per layer)
    bf16_t* owT   = wvT   + (size_t)NL_ * 2 * D_ * D_;
    bf16_t* f1T   = owT   + (size_t)NL_ * D_ * D_;     // NL*FF*D
    bf16_t* f2T   = f1T   + (size_t)NL_ * FF_ * D_;    // NL*D*FF
    float*  b1v   = (float*)(f2T + (size_t)NL_ * D_ * FF_); // NL*2D fp32
    float*  pK    = b1v + (size_t)NL_ * 2 * D_;        // 2*MR*D fp32 split-K partials
    bf16_t* hn_bf = (bf16_t*)d_ws;                     // MR*D (2 MB)
    bf16_t* emb_bf = hn_bf + (size_t)MR_ * D_;         // V*D bf16 (32.8 MB)
    const bool big_ws =
        ws_size >= ((size_t)MR_ * D_ + (size_t)V_ * D_) * sizeof(bf16_t);

    gather_kernel<<<MR_, 128, 0, stream>>>(tokens, embed, h);

    // Pre-transpose + convert all weights to bf16 [N][K]
    // Fused t1|v weight: layer i rows [0,D) = cp_w1^T, rows [D,2D) = val_w^T
    tconv_kernel<<<dim3(16, 16, NL_), 256, 0, stream>>>(cp_w1, wvT, D_, D_, (size_t)D_ * D_, (size_t)2 * D_ * D_);
    tconv_kernel<<<dim3(16, 16, NL_), 256, 0, stream>>>(val_w, wvT + (size_t)D_ * D_, D_, D_, (size_t)D_ * D_, (size_t)2 * D_ * D_);
    bconcat_kernel<<<NL_, 512, 0, stream>>>(cp_b1, val_b, b1v);
    tconv_kernel<<<dim3(16, 16, NL_), 256, 0, stream>>>(out_w, owT, D_, D_, (size_t)D_ * D_, (size_t)D_ * D_);
    tconv_kernel<<<dim3(64, 16, NL_), 256, 0, stream>>>(ffn_w1, f1T, D_, FF_, (size_t)D_ * FF_, (size_t)D_ * FF_);
    tconv_kernel<<<dim3(16, 64, NL_), 256, 0, stream>>>(ffn_w2, f2T, FF_, D_, (size_t)FF_ * D_, (size_t)FF_ * D_);
    // embed is already [N=V][K=D]: straight convert to bf16 for the head GEMM
    if (big_ws)
        cvt_kernel<<<(V_ * D_) / 2048, 256, 0, stream>>>(embed, emb_bf);

    for (int i = 0; i < NL_; ++i) {
        // x = LN(h): explicit only for layer 0 (fused into prev sumk_ln after)
        if (i == 0)
            ln_kernel<<<MR_, 256, 0, stream>>>(h, ln1_g, ln1_b, x, x_bf);
        // t1v = [tanh(x @ cp_w1 + cp_b1) | x @ val_w + val_b]  (fused, N=1024)
        mgemm<64, 64, 3, 64, false><<<dim3(16, 32, 1), 256, 0, stream>>>(
            x_bf, wvT + (size_t)i * 2 * D_ * D_, b1v + (size_t)i * 2 * D_,
            nullptr, nullptr, t1v, nullptr, MR_, 2 * D_, D_, FLAG_TANHLO, 0, 0, 0, 1);
        // csb = bf16 [cos|sin] phases (reads t1 = cols [0,D) of t1v)
        phase_kernel<<<MR_ / 4, 256, 0, stream>>>(
            t1v, cp_w2 + (size_t)i * D_ * K_, cp_b2 + i * K_,
            pos_scale, content_scale, i, csb);
        // vT (bf16, [b][D][L]) from cols [D,2D) of t1v — coalesced LDS transpose
        tconv_kernel<<<dim3(16, 32, B_), 256, 0, stream>>>(
            t1v + D_, vT_bf, L_, 2 * D_, (size_t)L_ * 2 * D_, (size_t)D_ * L_);
        // r = (tri(CS@CS^T) @ v) * inv_norm — fused score+PV (one dispatch)
        phattn_kernel<<<dim3(D_ / 64, L_ / 64, B_), 256, 0, stream>>>(
            csb, vT_bf, r);
        // r_bf = LN(r)
        ln_kernel<<<MR_, 256, 0, stream>>>(r, oln_g + i * D_, oln_b + i * D_, nullptr, r_bf);
        // h = h + x + (r_bf @ out_w + out_b)  (BN=32 -> 512 blocks, 2/CU)
        mgemm<64, 32, 3, 64, false><<<dim3(16, 32, 1), 256, 0, stream>>>(
            r_bf, owT + (size_t)i * D_ * D_, out_b + i * D_,
            h, x, h, nullptr, MR_, D_, D_, 0, 0, 0, 0, 1);
        // y_bf = LN(h)
        ln_kernel<<<MR_, 256, 0, stream>>>(h, ln2_g + i * D_, ln2_b + i * D_, nullptr, y_bf);
        // ff_bf = gelu(y @ ffn_w1 + b1)  (bf16 only; 64² -> 1024 blocks, 3/CU)
        mgemm<64, 64, 3, 64, false><<<dim3(32, 32, 1), 256, 0, stream>>>(
            y_bf, f1T + (size_t)i * FF_ * D_, ffn_b1 + i * FF_,
            nullptr, nullptr, nullptr, ff_bf, MR_, FF_, D_, FLAG_GELU, 0, 0, 0, 1);
        // ffn2 split-K=2, BN=32 -> 1024 blocks, 4/CU
        mgemm<64, 32, 3, 64, false><<<dim3(16, 32, 2), 256, 0, stream>>>(
            ff_bf, f2T + (size_t)i * D_ * FF_, nullptr,
            nullptr, nullptr, pK, nullptr, MR_, D_, FF_, FLAG_HALFK,
            (long long)(FF_ / 2), (long long)(FF_ / 2), (long long)MR_ * D_, 1);
        // h += pK0 + pK1 + ffn_b2, fused with next LN
        if (i < NL_ - 1) {
            sumk_ln_kernel<<<MR_, 256, 0, stream>>>(
                pK, pK + (size_t)MR_ * D_, ffn_b2 + i * D_, h,
                ln1_g + (i + 1) * D_, ln1_b + (i + 1) * D_, x, x_bf);
        } else {
            sumk_ln_kernel<<<MR_, 256, 0, stream>>>(
                pK, pK + (size_t)MR_ * D_, ffn_b2 + i * D_, h,
                no_g, no_b, nullptr, hn_bf);
        }
    }

    // out = hn @ embed^T + head_b   (BN=64 -> 36 KB LDS -> 4 blocks/CU)
    if (big_ws) {
        mgemm<128, 64, 3, 32, false><<<dim3(V_ / 64, MR_ / 128, 1), 256, 0, stream>>>(
            hn_bf, emb_bf, head_b, nullptr, nullptr, out, nullptr,
            MR_, V_, D_, 0, 0, 0, 0, 1);
    } else {
        mgemm<128, 128, 1, 32, true><<<dim3(V_ / 128, MR_ / 128, 1), 256, 0, stream>>>(
            hn_bf, embed, head_b, nullptr, nullptr, out, nullptr,
            MR_, V_, D_, 0, 0, 0, 0, 1);
    }
}